// Round 9
// baseline (491.701 us; speedup 1.0000x reference)
//
#include <hip/hip_runtime.h>
#include <hip/hip_bf16.h>
#include <math.h>

// EnhancedTransformerBlock on MI355X — Round 9: true 8-phase GEMM (m201-style).
// K-half LDS slots [256][32] (ring of 4 per matrix): fragment reads are 1KiB
// contiguous per 16-row fragment -> conflict-free without swizzle. Per K-tile:
// 4 phases {ds_read || stage half-tile -> barrier -> lgkm0+schedbar -> setprio
// -> 16 MFMA -> counted vmcnt -> barrier}. Staging 1.5-2 tiles ahead; steady
// vmcnt(8)/(6), peeled 2-tile tail. attn v3 / adaLN unchanged from round 8.

#define HDIM 1024
#define NHEAD 16
#define DHEAD 64
#define NBATCH 8
#define NSEQ 1024
#define NTOK (NBATCH * NSEQ)   // 8192
#define QKVSTR 3072
#define LNEPS 1e-5f
#define LOG2E_8 0.180336880f   // log2(e)/8

using f32x4 = __attribute__((ext_vector_type(4))) float;
using s16x8 = __attribute__((ext_vector_type(8))) short;
using u16x8 = __attribute__((ext_vector_type(8))) unsigned short;

enum { ACT_NONE = 0, ACT_GELU = 1, ACT_RELU = 2, ACT_SIG = 3 };

__device__ inline float bf2f(unsigned short u) {
    union { unsigned u; float f; } t; t.u = ((unsigned)u) << 16; return t.f;
}
__device__ inline unsigned short f2bf(float f) {
    __hip_bfloat16 h = __float2bfloat16(f);
    return *reinterpret_cast<unsigned short*>(&h);
}
__device__ inline float gelu_f(float t) {
    const float u = t * (0.7978845608f + 0.0356774081f * t * t);
    const float e = __expf(2.f * u);
    const float th = 1.f - 2.f / (e + 1.f);
    return 0.5f * t * (1.f + th);
}

#define GLDS16(g, l) __builtin_amdgcn_global_load_lds( \
    (__attribute__((address_space(1))) void*)(g),      \
    (__attribute__((address_space(3))) void*)(l), 16, 0, 0)
#define MFMA16(a, b, c) __builtin_amdgcn_mfma_f32_16x16x32_bf16(a, b, c, 0, 0, 0)
#define BAR() __builtin_amdgcn_s_barrier()
#define LGKM0() do { asm volatile("s_waitcnt lgkmcnt(0)" ::: "memory"); \
                     __builtin_amdgcn_sched_barrier(0); } while (0)

template<int N> __device__ __forceinline__ void vmwait() {
    asm volatile("s_waitcnt vmcnt(%0)" :: "i"(N) : "memory");
}

// ---------------------------------------------------------------------------
__global__ __launch_bounds__(256)
void cast_bf16_k(const float* __restrict__ in, unsigned short* __restrict__ out, int n4)
{
    for (int i = blockIdx.x * 256 + threadIdx.x; i < n4; i += gridDim.x * 256) {
        float4 v = ((const float4*)in)[i];
        ushort4 o;
        o.x = f2bf(v.x); o.y = f2bf(v.y); o.z = f2bf(v.z); o.w = f2bf(v.w);
        ((ushort4*)out)[i] = o;
    }
}

// ---------------------------------------------------------------------------
__global__ __launch_bounds__(256)
void concat3_k(const float* __restrict__ a, const float* __restrict__ b,
               const float* __restrict__ c, float* __restrict__ o)
{
    int i = blockIdx.x * 256 + threadIdx.x;
    o[i] = i < 1024 ? a[i] : (i < 2048 ? b[i - 1024] : c[i - 2048]);
}

// ---------------------------------------------------------------------------
__global__ __launch_bounds__(256)
void transpose_cast_k(const float* __restrict__ W, unsigned short* __restrict__ Wt,
                      int K, int N)
{
    __shared__ float tile[32][33];
    const int tx = threadIdx.x, ty = threadIdx.y;
    const int k0 = blockIdx.y * 32, n0 = blockIdx.x * 32;
#pragma unroll
    for (int r = 0; r < 32; r += 8)
        tile[ty + r][tx] = W[(size_t)(k0 + ty + r) * N + n0 + tx];
    __syncthreads();
#pragma unroll
    for (int r = 0; r < 32; r += 8)
        Wt[(size_t)(n0 + ty + r) * K + k0 + tx] = f2bf(tile[tx][ty + r]);
}

__global__ __launch_bounds__(256)
void transpose_cast4_k(const float* __restrict__ W0, const float* __restrict__ W1,
                       const float* __restrict__ W2, const float* __restrict__ W3,
                       unsigned short* __restrict__ Wt)
{
    __shared__ float tile[32][33];
    const int z = blockIdx.z;
    const float* W = z == 0 ? W0 : z == 1 ? W1 : z == 2 ? W2 : W3;
    unsigned short* dst = Wt + (size_t)z * HDIM * HDIM;
    const int tx = threadIdx.x, ty = threadIdx.y;
    const int k0 = blockIdx.y * 32, n0 = blockIdx.x * 32;
#pragma unroll
    for (int r = 0; r < 32; r += 8)
        tile[ty + r][tx] = W[(size_t)(k0 + ty + r) * HDIM + n0 + tx];
    __syncthreads();
#pragma unroll
    for (int r = 0; r < 32; r += 8)
        dst[(size_t)(n0 + ty + r) * HDIM + k0 + tx] = f2bf(tile[tx][ty + r]);
}

// ---------------------------------------------------------------------------
__global__ __launch_bounds__(256)
void transpose_v_k(const unsigned short* __restrict__ vb, unsigned short* __restrict__ vtb)
{
    __shared__ unsigned short t[64][72];
    const int tid = threadIdx.x;
    const int b = blockIdx.z, h = blockIdx.y;
    const int s0 = blockIdx.x * 64;
    {
        const int r = tid >> 3, c = (tid & 7) * 8;
        *(u16x8*)&t[r][c] =
            *(const u16x8*)&vb[((size_t)(b * NSEQ + s0 + r)) * QKVSTR + h * DHEAD + c];
        *(u16x8*)&t[r + 32][c] =
            *(const u16x8*)&vb[((size_t)(b * NSEQ + s0 + r + 32)) * QKVSTR + h * DHEAD + c];
    }
    __syncthreads();
    {
        const int d = tid & 63, sc = (tid >> 6) * 16;
        u16x8 o0, o1;
#pragma unroll
        for (int i = 0; i < 8; ++i) o0[i] = t[sc + i][d];
#pragma unroll
        for (int i = 0; i < 8; ++i) o1[i] = t[sc + 8 + i][d];
        unsigned short* dst = &vtb[((size_t)((b * NHEAD + h) * DHEAD + d)) * NSEQ + s0 + sc];
        *(u16x8*)dst = o0;
        *(u16x8*)(dst + 8) = o1;
    }
}

// ---------------------------------------------------------------------------
// 8-phase GEMM. C[M,N] = act(A[M,K] @ Bt[N,K]^T + bias (+add)). BM=256, BK=64.
// 512 threads (8 waves). BN=256: 2Mx4N waves; BN=128: 4Mx2N waves.
// LDS: ring of 4 K-half slots per matrix, [rows][32] (64B row stride).
// ---------------------------------------------------------------------------
template<int BN, int ACT, bool HAS_ADD, bool OUT_BF>
__global__ __launch_bounds__(512, 1)
void gemm_ph8_k(const unsigned short* __restrict__ A, const unsigned short* __restrict__ Bt,
                const float* __restrict__ bias, const float* __restrict__ add,
                void* __restrict__ Cv, int M, int N, int K)
{
    extern __shared__ __align__(16) unsigned short lds[];
    constexpr int BM = 256;
    constexpr int WN = (BN == 256) ? 4 : 2;
    constexpr int WM = 8 / WN;                 // 2 or 4
    constexpr int WROWS = BM / WM;             // 128 or 64
    constexpr int WCOLS = BN / WN;             // 64
    constexpr int MREP = WROWS / 16;           // 8 or 4
    constexpr int ASLOT = BM * 32;             // 8192 shorts
    constexpr int BSLOT = BN * 32;             // 8192 or 4096 shorts

    const int tid = threadIdx.x;
    const int lane = tid & 63;
    const int w = tid >> 6;
    const int wr = w / WN;
    const int wc = w % WN;
    const int m0 = blockIdx.y * BM;
    const int n0 = blockIdx.x * BN;
    const int fr = lane & 15;
    const int fo = lane >> 4;

    const int srow = lane >> 2;        // 0..15
    const int sk8 = (lane & 3) * 8;

    f32x4 acc[MREP][4] = {};

    // stage A K-half: 2 x global_load_lds (32 rows/wave)
    auto stA = [&](int t, int kh) {
        unsigned short* dst = lds + ((2 * t + kh) & 3) * ASLOT + (w * 32) * 32;
        const unsigned short* src = A + (size_t)(m0 + w * 32 + srow) * K + t * 64 + kh * 32 + sk8;
        GLDS16(src, dst);
        GLDS16(src + (size_t)16 * K, dst + 16 * 32);
    };
    auto stB = [&](int t, int kh) {
        unsigned short* base = lds + 4 * ASLOT + ((2 * t + kh) & 3) * BSLOT;
        if constexpr (BN == 256) {
            unsigned short* dst = base + (w * 32) * 32;
            const unsigned short* src = Bt + (size_t)(n0 + w * 32 + srow) * K + t * 64 + kh * 32 + sk8;
            GLDS16(src, dst);
            GLDS16(src + (size_t)16 * K, dst + 16 * 32);
        } else {
            unsigned short* dst = base + (w * 16) * 32;
            const unsigned short* src = Bt + (size_t)(n0 + w * 16 + srow) * K + t * 64 + kh * 32 + sk8;
            GLDS16(src, dst);
        }
    };

    const int NT = K / 64;
    // prologue: A0B0(0), A1B1(0), A0B0(1); then ensure A0B0(0) landed.
    stA(0, 0); stB(0, 0);
    stA(0, 1); stB(0, 1);
    stA(1, 0); stB(1, 0);
    if constexpr (BN == 256) vmwait<8>(); else vmwait<6>();
    BAR();

    for (int t = 0; t < NT; ++t) {
        const bool s1 = (t + 1 < NT);
        const bool s2 = (t + 2 < NT);
        const int tail = (t == NT - 1) ? 2 : ((t == NT - 2) ? 1 : 0);
        const int sl0 = (2 * t) & 3;
        const int sl1 = (2 * t + 1) & 3;

        if constexpr (BN == 256) {
            s16x8 afr[4], bfr[4];
            // ---- p0: mh0 kk0
#pragma unroll
            for (int i = 0; i < 4; ++i)
                afr[i] = *(const s16x8*)(lds + sl0 * ASLOT + (wr * 128 + i * 16 + fr) * 32 + fo * 8);
#pragma unroll
            for (int j = 0; j < 4; ++j)
                bfr[j] = *(const s16x8*)(lds + 4 * ASLOT + sl0 * BSLOT + (wc * 64 + j * 16 + fr) * 32 + fo * 8);
            if (s1) stA(t + 1, 1);
            BAR(); LGKM0();
            __builtin_amdgcn_s_setprio(1);
#pragma unroll
            for (int i = 0; i < 4; ++i)
#pragma unroll
                for (int j = 0; j < 4; ++j)
                    acc[i][j] = MFMA16(afr[i], bfr[j], acc[i][j]);
            __builtin_amdgcn_s_setprio(0);
            BAR();
            // ---- p1: mh1 kk0 (reuse B)
#pragma unroll
            for (int i = 0; i < 4; ++i)
                afr[i] = *(const s16x8*)(lds + sl0 * ASLOT + (wr * 128 + 64 + i * 16 + fr) * 32 + fo * 8);
            if (s1) stB(t + 1, 1);
            BAR(); LGKM0();
            __builtin_amdgcn_s_setprio(1);
#pragma unroll
            for (int i = 0; i < 4; ++i)
#pragma unroll
                for (int j = 0; j < 4; ++j)
                    acc[4 + i][j] = MFMA16(afr[i], bfr[j], acc[4 + i][j]);
            __builtin_amdgcn_s_setprio(0);
            if (tail < 2) vmwait<8>(); else vmwait<0>();
            BAR();
            // ---- p2: mh1 kk1
#pragma unroll
            for (int i = 0; i < 4; ++i)
                afr[i] = *(const s16x8*)(lds + sl1 * ASLOT + (wr * 128 + 64 + i * 16 + fr) * 32 + fo * 8);
#pragma unroll
            for (int j = 0; j < 4; ++j)
                bfr[j] = *(const s16x8*)(lds + 4 * ASLOT + sl1 * BSLOT + (wc * 64 + j * 16 + fr) * 32 + fo * 8);
            if (s2) stA(t + 2, 0);
            BAR(); LGKM0();
            __builtin_amdgcn_s_setprio(1);
#pragma unroll
            for (int i = 0; i < 4; ++i)
#pragma unroll
                for (int j = 0; j < 4; ++j)
                    acc[4 + i][j] = MFMA16(afr[i], bfr[j], acc[4 + i][j]);
            __builtin_amdgcn_s_setprio(0);
            BAR();
            // ---- p3: mh0 kk1
#pragma unroll
            for (int i = 0; i < 4; ++i)
                afr[i] = *(const s16x8*)(lds + sl1 * ASLOT + (wr * 128 + i * 16 + fr) * 32 + fo * 8);
            if (s2) stB(t + 2, 0);
            BAR(); LGKM0();
            __builtin_amdgcn_s_setprio(1);
#pragma unroll
            for (int i = 0; i < 4; ++i)
#pragma unroll
                for (int j = 0; j < 4; ++j)
                    acc[i][j] = MFMA16(afr[i], bfr[j], acc[i][j]);
            __builtin_amdgcn_s_setprio(0);
            if (tail == 0) vmwait<8>(); else if (tail == 1) vmwait<4>();
            BAR();
        } else {
            s16x8 afr[4], bfr[4];
            // ---- p0: kk0
#pragma unroll
            for (int i = 0; i < 4; ++i)
                afr[i] = *(const s16x8*)(lds + sl0 * ASLOT + (wr * 64 + i * 16 + fr) * 32 + fo * 8);
#pragma unroll
            for (int j = 0; j < 4; ++j)
                bfr[j] = *(const s16x8*)(lds + 4 * ASLOT + sl0 * BSLOT + (wc * 64 + j * 16 + fr) * 32 + fo * 8);
            if (s1) { stA(t + 1, 1); stB(t + 1, 1); }
            BAR(); LGKM0();
            __builtin_amdgcn_s_setprio(1);
#pragma unroll
            for (int i = 0; i < 4; ++i)
#pragma unroll
                for (int j = 0; j < 4; ++j)
                    acc[i][j] = MFMA16(afr[i], bfr[j], acc[i][j]);
            __builtin_amdgcn_s_setprio(0);
            if (tail < 2) vmwait<6>(); else vmwait<0>();
            BAR();
            // ---- p1: kk1
#pragma unroll
            for (int i = 0; i < 4; ++i)
                afr[i] = *(const s16x8*)(lds + sl1 * ASLOT + (wr * 64 + i * 16 + fr) * 32 + fo * 8);
#pragma unroll
            for (int j = 0; j < 4; ++j)
                bfr[j] = *(const s16x8*)(lds + 4 * ASLOT + sl1 * BSLOT + (wc * 64 + j * 16 + fr) * 32 + fo * 8);
            if (s2) { stA(t + 2, 0); stB(t + 2, 0); }
            BAR(); LGKM0();
            __builtin_amdgcn_s_setprio(1);
#pragma unroll
            for (int i = 0; i < 4; ++i)
#pragma unroll
                for (int j = 0; j < 4; ++j)
                    acc[i][j] = MFMA16(afr[i], bfr[j], acc[i][j]);
            __builtin_amdgcn_s_setprio(0);
            if (tail == 0) vmwait<6>(); else if (tail == 1) vmwait<3>();
            BAR();
        }
    }

    // ---- epilogue
    float bv[4];
#pragma unroll
    for (int j = 0; j < 4; ++j)
        bv[j] = bias[n0 + wc * WCOLS + j * 16 + fr];
#pragma unroll
    for (int i = 0; i < MREP; ++i) {
        const int rbase = (BN == 256) ? ((i >> 2) * 64 + (i & 3) * 16) : (i * 16);
#pragma unroll
        for (int j = 0; j < 4; ++j) {
            const int gn = n0 + wc * WCOLS + j * 16 + fr;
#pragma unroll
            for (int r = 0; r < 4; ++r) {
                const int gm = m0 + wr * WROWS + rbase + fo * 4 + r;
                float t = acc[i][j][r] + bv[j];
                if (HAS_ADD) t += add[(size_t)gm * N + gn];
                if (ACT == ACT_GELU)      t = gelu_f(t);
                else if (ACT == ACT_RELU) t = fmaxf(t, 0.f);
                else if (ACT == ACT_SIG)  t = 1.f / (1.f + __expf(-t));
                if (OUT_BF) ((unsigned short*)Cv)[(size_t)gm * N + gn] = f2bf(t);
                else        ((float*)Cv)[(size_t)gm * N + gn] = t;
            }
        }
    }
}

// ---------------------------------------------------------------------------
// Old 2-phase 128x128 GEMM (kept for gate1 N=512 only).
// ---------------------------------------------------------------------------
template<int BM, int BN, int ACT, bool HAS_ADD, bool OUT_BF>
__global__ __launch_bounds__(512, (BM == 128) ? 4 : 2)
void gemm8_k(const unsigned short* __restrict__ A, const unsigned short* __restrict__ Bt,
             const float* __restrict__ bias, const float* __restrict__ add,
             void* __restrict__ Cv, int M, int N, int K)
{
    extern __shared__ __align__(16) unsigned short lds[];
    constexpr int BK = 64;
    constexpr int WN = 2;
    constexpr int WM = 4;
    constexpr int MREP = BM / (WM * 16);
    constexpr int NREP = BN / (WN * 16);
    constexpr int ASZ = BM * BK;
    constexpr int BSZ = BN * BK;
    constexpr int AR = BM / 64;
    constexpr int BR = BN / 64;
    constexpr int VM = AR + BR;

    const int tid = threadIdx.x;
    const int lane = tid & 63;
    const int w = tid >> 6;
    const int wr = w / WN;
    const int wc = w % WN;
    const int m0 = blockIdx.y * BM;
    const int n0 = blockIdx.x * BN;
    const int fr = lane & 15;
    const int fo = lane >> 4;

    const int srow = tid >> 3;
    const int sslot = (tid & 7) ^ (srow & 7);
    const size_t a_base = (size_t)(m0 + srow) * K + sslot * 8;
    const size_t b_base = (size_t)(n0 + srow) * K + sslot * 8;

    f32x4 acc[MREP][NREP] = {};

    auto stage = [&](int t) {
        const int buf = t & 1;
        unsigned short* ad = lds + buf * ASZ + w * 512;
        unsigned short* bd = lds + 2 * ASZ + buf * BSZ + w * 512;
        const unsigned short* as_ = A + a_base + (size_t)t * BK;
        const unsigned short* bs_ = Bt + b_base + (size_t)t * BK;
#pragma unroll
        for (int j = 0; j < AR; ++j)
            GLDS16(as_ + (size_t)j * 64 * K, ad + j * 4096);
#pragma unroll
        for (int j = 0; j < BR; ++j)
            GLDS16(bs_ + (size_t)j * 64 * K, bd + j * 4096);
    };

    const int NT = K / BK;
    stage(0);

    for (int t = 0; t < NT; ++t) {
        if (t + 1 < NT) {
            stage(t + 1);
            asm volatile("s_waitcnt vmcnt(%0)" :: "i"(VM) : "memory");
        } else {
            asm volatile("s_waitcnt vmcnt(0)" ::: "memory");
        }
        __builtin_amdgcn_s_barrier();

        const char* Ab = (const char*)(lds + (t & 1) * ASZ);
        const char* Bb = (const char*)(lds + 2 * ASZ + (t & 1) * BSZ);

        s16x8 af[MREP / 2][2], bfr[NREP][2];
#pragma unroll
        for (int ph = 0; ph < 2; ++ph) {
#pragma unroll
            for (int i = 0; i < MREP / 2; ++i) {
                const int row = wr * (BM / WM) + (ph * (MREP / 2) + i) * 16 + fr;
                const int sw = (row & 7) << 4;
#pragma unroll
                for (int kk = 0; kk < 2; ++kk)
                    af[i][kk] = *(const s16x8*)(Ab + row * 128 + ((kk * 64 + fo * 16) ^ sw));
            }
            if (ph == 0) {
#pragma unroll
                for (int j = 0; j < NREP; ++j) {
                    const int row = wc * 64 + j * 16 + fr;
                    const int sw = (row & 7) << 4;
#pragma unroll
                    for (int kk = 0; kk < 2; ++kk)
                        bfr[j][kk] = *(const s16x8*)(Bb + row * 128 + ((kk * 64 + fo * 16) ^ sw));
                }
            }
            __builtin_amdgcn_s_setprio(1);
#pragma unroll
            for (int i = 0; i < MREP / 2; ++i)
#pragma unroll
                for (int j = 0; j < NREP; ++j)
#pragma unroll
                    for (int kk = 0; kk < 2; ++kk)
                        acc[ph * (MREP / 2) + i][j] =
                            MFMA16(af[i][kk], bfr[j][kk], acc[ph * (MREP / 2) + i][j]);
            __builtin_amdgcn_s_setprio(0);
        }
        asm volatile("s_waitcnt lgkmcnt(0)" ::: "memory");
        __builtin_amdgcn_sched_barrier(0);
        __builtin_amdgcn_s_barrier();
    }

    float bv[NREP];
#pragma unroll
    for (int j = 0; j < NREP; ++j)
        bv[j] = bias[n0 + wc * 64 + j * 16 + fr];
#pragma unroll
    for (int i = 0; i < MREP; ++i) {
#pragma unroll
        for (int j = 0; j < NREP; ++j) {
            const int gn = n0 + wc * 64 + j * 16 + fr;
#pragma unroll
            for (int r = 0; r < 4; ++r) {
                const int gm = m0 + wr * (BM / WM) + i * 16 + fo * 4 + r;
                float t = acc[i][j][r] + bv[j];
                if (HAS_ADD) t += add[(size_t)gm * N + gn];
                if (ACT == ACT_GELU)      t = gelu_f(t);
                else if (ACT == ACT_RELU) t = fmaxf(t, 0.f);
                else if (ACT == ACT_SIG)  t = 1.f / (1.f + __expf(-t));
                if (OUT_BF) ((unsigned short*)Cv)[(size_t)gm * N + gn] = f2bf(t);
                else        ((float*)Cv)[(size_t)gm * N + gn] = t;
            }
        }
    }
}

// ---------------------------------------------------------------------------
// MFMA flash attention v3 (round-8, unchanged).
// ---------------------------------------------------------------------------
__global__ __launch_bounds__(512, 6)
void attn_k(const unsigned short* __restrict__ QKVb, const unsigned short* __restrict__ Vtb,
            unsigned short* __restrict__ Cb)
{
    __shared__ alignas(16) unsigned short Ks[2][64 * 64];
    __shared__ alignas(16) unsigned short Vs[2][64 * 64];
    __shared__ alignas(16) unsigned short Ps[8][16 * 72];

    const int tid = threadIdx.x;
    const int lane = tid & 63;
    const int wid = tid >> 6;
    const int L = blockIdx.x;
    const int xcd = L & 7, s = L >> 3;
    const int bh = xcd + ((s >> 3) << 3);
    const int qt = s & 7;
    const int b = bh >> 4, h = bh & 15;
    const int q0 = qt * 128 + wid * 16;

    const int kcol = lane & 15;
    const int kofs = (lane >> 4) * 8;
    const size_t qoff = ((size_t)(b * NSEQ + q0 + kcol)) * QKVSTR + h * DHEAD + kofs;
    const s16x8 qf0 = *(const s16x8*)(QKVb + qoff);
    const s16x8 qf1 = *(const s16x8*)(QKVb + qoff + 32);

    f32x4 accO[4] = {};
    float mrow[4] = {-1e30f, -1e30f, -1e30f, -1e30f};
    float lsum[4] = {0.f, 0.f, 0.f, 0.f};

    const int lr = lane >> 3;
    const int swz8 = (((lane & 7) ^ lr)) * 8;
    const size_t kbase  = ((size_t)(b * NSEQ)) * QKVSTR + HDIM + h * DHEAD;
    const size_t vtbase = ((size_t)(bh * DHEAD)) * NSEQ;

    unsigned short* const pw = &Ps[wid][0];
    const int prow = (lane >> 4) * 4;

    auto stage = [&](int kt, int buf) {
        const int rowb = wid * 8;
        GLDS16(QKVb + kbase + (size_t)(kt * 64 + rowb + lr) * QKVSTR + swz8,
               Ks[buf] + rowb * 64);
        GLDS16(Vtb + vtbase + (size_t)(rowb + lr) * NSEQ + kt * 64 + swz8,
               Vs[buf] + rowb * 64);
    };

    stage(0, 0);
    asm volatile("s_waitcnt vmcnt(0)" ::: "memory");
    __syncthreads();

    for (int kt = 0; kt < NSEQ / 64; ++kt) {
        const int cur = kt & 1;
        if (kt + 1 < NSEQ / 64) stage(kt + 1, cur ^ 1);

        f32x4 sa[4];
#pragma unroll
        for (int jt = 0; jt < 4; ++jt) {
            const int kr = jt * 16 + kcol;
            const unsigned swz = ((unsigned)(kr & 7)) << 4;
            const s16x8 kf0 = *(const s16x8*)((const char*)Ks[cur] + kr * 128 + ((kofs * 2) ^ swz));
            const s16x8 kf1 = *(const s16x8*)((const char*)Ks[cur] + kr * 128 + ((64 + kofs * 2) ^ swz));
            f32x4 t = {};
            t = MFMA16(qf0, kf0, t);
            t = MFMA16(qf1, kf1, t);
            sa[jt] = t * LOG2E_8;
        }

        float lmax[4];
#pragma unroll
        for (int r = 0; r < 4; ++r)
            lmax[r] = fmaxf(fmaxf(sa[0][r], sa[1][r]), fmaxf(sa[2][r], sa[3][r]));
        const float guard = fmaxf(fmaxf(lmax[0] - mrow[0], lmax[1] - mrow[1]),
                                  fmaxf(lmax[2] - mrow[2], lmax[3] - mrow[3]));
        if (!__all(guard <= 8.f)) {
#pragma unroll
            for (int r = 0; r < 4; ++r) {
                float m = lmax[r];
                m = fmaxf(m, __shfl_xor(m, 1));
                m = fmaxf(m, __shfl_xor(m, 2));
                m = fmaxf(m, __shfl_xor(m, 4));
                m = fmaxf(m, __shfl_xor(m, 8));
                const float mn = fmaxf(mrow[r], m);
                const float corr = exp2f(mrow[r] - mn);
                mrow[r] = mn;
                lsum[r] *= corr;
#pragma unroll
                for (int dt = 0; dt < 4; ++dt) accO[dt][r] *= corr;
            }
        }
#pragma unroll
        for (int r = 0; r < 4; ++r) {
#pragma unroll
            for (int jt = 0; jt < 4; ++jt) {
                const float p = exp2f(sa[jt][r] - mrow[r]);
                pw[(prow + r) * 72 + jt * 16 + kcol] = f2bf(p);
                lsum[r] += p;
            }
        }

#pragma unroll
        for (int kc = 0; kc < 2; ++kc) {
            const s16x8 pa = *(const s16x8*)(pw + kcol * 72 + kc * 32 + kofs);
#pragma unroll
            for (int dt = 0; dt < 4; ++dt) {
                const int dr = dt * 16 + kcol;
                const unsigned swz = ((unsigned)(dr & 7)) << 4;
                const s16x8 vf = *(const s16x8*)((const char*)Vs[cur] + dr * 128 +
                                                 ((kc * 64 + kofs * 2) ^ swz));
                accO[dt] = MFMA16(pa, vf, accO[dt]);
            }
        }

        if (kt + 1 < NSEQ / 64) asm volatile("s_waitcnt vmcnt(0)" ::: "memory");
        __builtin_amdgcn_s_barrier();
    }

#pragma unroll
    for (int r = 0; r < 4; ++r) {
        lsum[r] += __shfl_xor(lsum[r], 1);
        lsum[r] += __shfl_xor(lsum[r], 2);
        lsum[r] += __shfl_xor(lsum[r], 4);
        lsum[r] += __shfl_xor(lsum[r], 8);
    }

    const size_t obase = ((size_t)(b * NSEQ + q0 + prow)) * HDIM + h * DHEAD;
#pragma unroll
    for (int r = 0; r < 4; ++r) {
        const float rl = 1.f / lsum[r];
#pragma unroll
        for (int dt = 0; dt < 4; ++dt)
            Cb[obase + (size_t)r * HDIM + dt * 16 + kcol] = f2bf(accO[dt][r] * rl);
    }
}

// ---------------------------------------------------------------------------
// ada-LayerNorm (unchanged)
// ---------------------------------------------------------------------------
template<int MODE, bool WRITE_BF>
__global__ __launch_bounds__(256)
void adaln_k(const float* __restrict__ a, const float* __restrict__ fo,
             const float* __restrict__ g, const float* __restrict__ vol,
             const float* __restrict__ lw, const float* __restrict__ lb,
             const float* __restrict__ gm, const float* __restrict__ bt,
             const float* __restrict__ vsw, const float* __restrict__ vsb,
             float* __restrict__ out, unsigned short* __restrict__ out_bf)
{
    const int tok = blockIdx.x;
    const int tid = threadIdx.x;
    const size_t base = (size_t)tok * HDIM + tid * 4;
    float v[4];
    {
        float4 va = *(const float4*)&a[base];
        if (MODE == 1) {
            float4 vf = *(const float4*)&fo[base];
            float4 vg = *(const float4*)&g[base];
            v[0] = va.x * (2.f - vg.x) + vf.x * vg.x;
            v[1] = va.y * (2.f - vg.y) + vf.y * vg.y;
            v[2] = va.z * (2.f - vg.z) + vf.z * vg.z;
            v[3] = va.w * (2.f - vg.w) + vf.w * vg.w;
        } else {
            v[0] = va.x; v[1] = va.y; v[2] = va.z; v[3] = va.w;
        }
    }
    float sum = v[0] + v[1] + v[2] + v[3];
    float sq  = v[0]*v[0] + v[1]*v[1] + v[2]*v[2] + v[3]*v[3];
#pragma unroll
    for (int off = 32; off > 0; off >>= 1) {
        sum += __shfl_down(sum, off);
        sq  += __shfl_down(sq, off);
    }
    __shared__ float ssum[4], ssq[4];
    const int wid = tid >> 6, lane = tid & 63;
    if (lane == 0) { ssum[wid] = sum; ssq[wid] = sq; }
    __syncthreads();
    const float tsum = ssum[0] + ssum[1] + ssum[2] + ssum[3];
    const float tsq  = ssq[0]  + ssq[1]  + ssq[2]  + ssq[3];
    const float mu   = tsum * (1.f / 1024.f);
    const float var  = tsq * (1.f / 1024.f) - mu * mu;
    const float rstd = rsqrtf(var + LNEPS);
    const float vsv  = 1.f / (1.f + __expf(-(vol[tok] * vsw[0] + vsb[0])));
    const float sca  = (1.f + vsv) * gm[0];
    const float off2 = bt[0];
    const float4 lwv = *(const float4*)&lw[tid * 4];
    const float4 lbv = *(const float4*)&lb[tid * 4];
    float r0 = ((v[0] - mu) * rstd * lwv.x + lbv.x) * sca + off2;
    float r1 = ((v[1] - mu) * rstd * lwv.y + lbv.y) * sca + off2;
    float r2 = ((v[2] - mu) * rstd * lwv.z + lbv.z) * sca + off2;
    float r3 = ((v[3] - mu) * rstd * lwv.w + lbv.w) * sca + off2;
    *(float4*)&out[base] = make_float4(r0, r1, r2, r3);
    if (WRITE_BF) {
        ushort4 ob;
        ob.x = f2bf(r0); ob.y = f2bf(r1); ob.z = f2bf(r2); ob.w = f2bf(r3);
        *(ushort4*)&out_bf[base] = ob;
    }
}

// ---------------------------------------------------------------------------
extern "C" void kernel_launch(void* const* d_in, const int* in_sizes, int n_in,
                              void* d_out, int out_size, void* d_ws, size_t ws_size,
                              hipStream_t stream)
{
    (void)in_sizes; (void)n_in; (void)out_size; (void)ws_size;
    const float* x    = (const float*)d_in[0];
    const float* vol  = (const float*)d_in[1];
    const float* Wq   = (const float*)d_in[2];  const float* bq  = (const float*)d_in[3];
    const float* Wk   = (const float*)d_in[4];  const float* bk  = (const float*)d_in[5];
    const float* Wv   = (const float*)d_in[6];  const float* bv  = (const float*)d_in[7];
    const float* Wo   = (const float*)d_in[8];  const float* bo  = (const float*)d_in[9];
    const float* ln1w = (const float*)d_in[10]; const float* ln1b = (const float*)d_in[11];
    const float* gm1  = (const float*)d_in[12]; const float* be1 = (const float*)d_in[13];
    const float* vs1w = (const float*)d_in[14]; const float* vs1b = (const float*)d_in[15];
    const float* fw1  = (const float*)d_in[16]; const float* fb1 = (const float*)d_in[17];
    const float* fw2  = (const float*)d_in[18]; const float* fb2 = (const float*)d_in[19];
    const float* gw1  = (const float*)d_in[20]; const float* gb1 = (const float*)d_in[21];
    const float* gw2  = (const float*)d_in[22]; const float* gb2 = (const float*)d_in[23];
    const float* ln2w = (const float*)d_in[24]; const float* ln2b = (const float*)d_in[25];
    const float* gm2  = (const float*)d_in[26]; const float* be2 = (const float*)d_in[27];
    const float* vs2w = (const float*)d_in[28]; const float* vs2b = (const float*)d_in[29];

    char* w = (char*)d_ws;
    auto MB = [](size_t v) { return v << 20; };
    unsigned short* wtqkv = (unsigned short*)(w + MB(0));   // 0-6
    unsigned short* wto   = (unsigned short*)(w + MB(6));
    unsigned short* wtf1  = (unsigned short*)(w + MB(8));
    unsigned short* wtf2  = (unsigned short*)(w + MB(16));
    unsigned short* wtg1  = (unsigned short*)(w + MB(24));
    unsigned short* wtg2  = (unsigned short*)(w + MB(25));
    unsigned short* xb   = (unsigned short*)(w + MB(26));   // 26-42
    unsigned short* qkvb = (unsigned short*)(w + MB(42));   // 42-90
    unsigned short* vtb  = (unsigned short*)(w + MB(90));   // 90-106
    unsigned short* cxb  = (unsigned short*)(w + MB(106));  // 106-122
    float*          ao   = (float*)(w + MB(122));           // 122-154
    float*          x1   = (float*)(w + MB(42));            // 42-74 (qkv dead)
    unsigned short* x1b  = (unsigned short*)(w + MB(74));   // 74-90
    unsigned short* hb   = (unsigned short*)(w + MB(90));   // 90-154
    float*          ffn  = (float*)(w + MB(154));           // 154-186
    unsigned short* ghb  = (unsigned short*)(w + MB(26));   // 26-34 (xb dead)
    float*          gg   = (float*)(w + MB(90));            // 90-122 (hb dead)
    float*          bqkv = (float*)(w + MB(186));

    dim3 blk(256);
    dim3 tb(32, 8);
    transpose_cast4_k<<<dim3(32, 32, 4), tb, 0, stream>>>(Wq, Wk, Wv, Wo, wtqkv);
    transpose_cast_k<<<dim3(4096/32, 1024/32), tb, 0, stream>>>(fw1, wtf1, 1024, 4096);
    transpose_cast_k<<<dim3(1024/32, 4096/32), tb, 0, stream>>>(fw2, wtf2, 4096, 1024);
    transpose_cast_k<<<dim3(512/32, 1024/32),  tb, 0, stream>>>(gw1, wtg1, 1024, 512);
    transpose_cast_k<<<dim3(1024/32, 512/32),  tb, 0, stream>>>(gw2, wtg2, 512, 1024);
    cast_bf16_k<<<2048, blk, 0, stream>>>(x, xb, NTOK * HDIM / 4);
    concat3_k<<<12, blk, 0, stream>>>(bq, bk, bv, bqkv);

    const size_t PH256 = 131072;   // 4*8192*2 + 4*8192*2 bytes
    const size_t PH128 = 98304;    // 4*8192*2 + 4*4096*2 bytes
    const size_t SH128 = (128 + 128) * 256;   // 64 KiB (old kernel)

    gemm_ph8_k<128, ACT_NONE, false, true><<<dim3(24, 32), 512, PH128, stream>>>(
        xb, wtqkv, bqkv, nullptr, qkvb, NTOK, QKVSTR, HDIM);
    transpose_v_k<<<dim3(NSEQ / 64, NHEAD, NBATCH), blk, 0, stream>>>(qkvb + 2048, vtb);
    attn_k<<<dim3(1024), 512, 0, stream>>>(qkvb, vtb, cxb);
    gemm_ph8_k<128, ACT_NONE, true, false><<<dim3(8, 32), 512, PH128, stream>>>(
        cxb, wto, bo, x, ao, NTOK, HDIM, HDIM);
    adaln_k<0, true><<<dim3(NTOK), blk, 0, stream>>>(
        ao, nullptr, nullptr, vol, ln1w, ln1b, gm1, be1, vs1w, vs1b, x1, x1b);
    gemm_ph8_k<256, ACT_GELU, false, true><<<dim3(16, 32), 512, PH256, stream>>>(
        x1b, wtf1, fb1, nullptr, hb, NTOK, 4096, HDIM);
    gemm_ph8_k<128, ACT_NONE, false, false><<<dim3(8, 32), 512, PH128, stream>>>(
        hb, wtf2, fb2, nullptr, ffn, NTOK, HDIM, 4096);
    gemm8_k<128, 128, ACT_RELU, false, true><<<dim3(4, 64), 512, SH128, stream>>>(
        x1b, wtg1, gb1, nullptr, ghb, NTOK, 512, HDIM);
    gemm_ph8_k<128, ACT_SIG, false, false><<<dim3(8, 32), 512, PH128, stream>>>(
        ghb, wtg2, gb2, nullptr, gg, NTOK, HDIM, 512);
    adaln_k<1, false><<<dim3(NTOK), blk, 0, stream>>>(
        x1, ffn, gg, vol, ln2w, ln2b, gm2, be2, vs2w, vs2b, (float*)d_out, nullptr);
}

// Round 10
// 476.291 us; speedup vs baseline: 1.0324x; 1.0324x over previous
//
#include <hip/hip_runtime.h>
#include <hip/hip_bf16.h>
#include <math.h>

// EnhancedTransformerBlock on MI355X — Round 10: 8-phase GEMM with FIXED swizzle.
// R9's [rows][32] K-half slots had row-stride 64B = 16 banks -> 8-way conflict
// (6.3M measured). Fix: XOR 16B-granule within row: s' = s ^ ((row>>1)&3),
// realized as pre-swizzled global source (per-lane const (lane&3)^((lane>>3)&3))
// + swizzled fragment read offset (per-lane const fo^((fr>>1)&3)). Both sides
// same involution (rule #21). Schedule/barriers/vmcnt identical to R9.

#define HDIM 1024
#define NHEAD 16
#define DHEAD 64
#define NBATCH 8
#define NSEQ 1024
#define NTOK (NBATCH * NSEQ)   // 8192
#define QKVSTR 3072
#define LNEPS 1e-5f
#define LOG2E_8 0.180336880f   // log2(e)/8

using f32x4 = __attribute__((ext_vector_type(4))) float;
using s16x8 = __attribute__((ext_vector_type(8))) short;
using u16x8 = __attribute__((ext_vector_type(8))) unsigned short;

enum { ACT_NONE = 0, ACT_GELU = 1, ACT_RELU = 2, ACT_SIG = 3 };

__device__ inline float bf2f(unsigned short u) {
    union { unsigned u; float f; } t; t.u = ((unsigned)u) << 16; return t.f;
}
__device__ inline unsigned short f2bf(float f) {
    __hip_bfloat16 h = __float2bfloat16(f);
    return *reinterpret_cast<unsigned short*>(&h);
}
__device__ inline float gelu_f(float t) {
    const float u = t * (0.7978845608f + 0.0356774081f * t * t);
    const float e = __expf(2.f * u);
    const float th = 1.f - 2.f / (e + 1.f);
    return 0.5f * t * (1.f + th);
}

#define GLDS16(g, l) __builtin_amdgcn_global_load_lds( \
    (__attribute__((address_space(1))) void*)(g),      \
    (__attribute__((address_space(3))) void*)(l), 16, 0, 0)
#define MFMA16(a, b, c) __builtin_amdgcn_mfma_f32_16x16x32_bf16(a, b, c, 0, 0, 0)
#define BAR() __builtin_amdgcn_s_barrier()
#define LGKM0() do { asm volatile("s_waitcnt lgkmcnt(0)" ::: "memory"); \
                     __builtin_amdgcn_sched_barrier(0); } while (0)

template<int N> __device__ __forceinline__ void vmwait() {
    asm volatile("s_waitcnt vmcnt(%0)" :: "i"(N) : "memory");
}

// ---------------------------------------------------------------------------
__global__ __launch_bounds__(256)
void cast_bf16_k(const float* __restrict__ in, unsigned short* __restrict__ out, int n4)
{
    for (int i = blockIdx.x * 256 + threadIdx.x; i < n4; i += gridDim.x * 256) {
        float4 v = ((const float4*)in)[i];
        ushort4 o;
        o.x = f2bf(v.x); o.y = f2bf(v.y); o.z = f2bf(v.z); o.w = f2bf(v.w);
        ((ushort4*)out)[i] = o;
    }
}

// ---------------------------------------------------------------------------
__global__ __launch_bounds__(256)
void concat3_k(const float* __restrict__ a, const float* __restrict__ b,
               const float* __restrict__ c, float* __restrict__ o)
{
    int i = blockIdx.x * 256 + threadIdx.x;
    o[i] = i < 1024 ? a[i] : (i < 2048 ? b[i - 1024] : c[i - 2048]);
}

// ---------------------------------------------------------------------------
__global__ __launch_bounds__(256)
void transpose_cast_k(const float* __restrict__ W, unsigned short* __restrict__ Wt,
                      int K, int N)
{
    __shared__ float tile[32][33];
    const int tx = threadIdx.x, ty = threadIdx.y;
    const int k0 = blockIdx.y * 32, n0 = blockIdx.x * 32;
#pragma unroll
    for (int r = 0; r < 32; r += 8)
        tile[ty + r][tx] = W[(size_t)(k0 + ty + r) * N + n0 + tx];
    __syncthreads();
#pragma unroll
    for (int r = 0; r < 32; r += 8)
        Wt[(size_t)(n0 + ty + r) * K + k0 + tx] = f2bf(tile[tx][ty + r]);
}

__global__ __launch_bounds__(256)
void transpose_cast4_k(const float* __restrict__ W0, const float* __restrict__ W1,
                       const float* __restrict__ W2, const float* __restrict__ W3,
                       unsigned short* __restrict__ Wt)
{
    __shared__ float tile[32][33];
    const int z = blockIdx.z;
    const float* W = z == 0 ? W0 : z == 1 ? W1 : z == 2 ? W2 : W3;
    unsigned short* dst = Wt + (size_t)z * HDIM * HDIM;
    const int tx = threadIdx.x, ty = threadIdx.y;
    const int k0 = blockIdx.y * 32, n0 = blockIdx.x * 32;
#pragma unroll
    for (int r = 0; r < 32; r += 8)
        tile[ty + r][tx] = W[(size_t)(k0 + ty + r) * HDIM + n0 + tx];
    __syncthreads();
#pragma unroll
    for (int r = 0; r < 32; r += 8)
        dst[(size_t)(n0 + ty + r) * HDIM + k0 + tx] = f2bf(tile[tx][ty + r]);
}

// ---------------------------------------------------------------------------
__global__ __launch_bounds__(256)
void transpose_v_k(const unsigned short* __restrict__ vb, unsigned short* __restrict__ vtb)
{
    __shared__ unsigned short t[64][72];
    const int tid = threadIdx.x;
    const int b = blockIdx.z, h = blockIdx.y;
    const int s0 = blockIdx.x * 64;
    {
        const int r = tid >> 3, c = (tid & 7) * 8;
        *(u16x8*)&t[r][c] =
            *(const u16x8*)&vb[((size_t)(b * NSEQ + s0 + r)) * QKVSTR + h * DHEAD + c];
        *(u16x8*)&t[r + 32][c] =
            *(const u16x8*)&vb[((size_t)(b * NSEQ + s0 + r + 32)) * QKVSTR + h * DHEAD + c];
    }
    __syncthreads();
    {
        const int d = tid & 63, sc = (tid >> 6) * 16;
        u16x8 o0, o1;
#pragma unroll
        for (int i = 0; i < 8; ++i) o0[i] = t[sc + i][d];
#pragma unroll
        for (int i = 0; i < 8; ++i) o1[i] = t[sc + 8 + i][d];
        unsigned short* dst = &vtb[((size_t)((b * NHEAD + h) * DHEAD + d)) * NSEQ + s0 + sc];
        *(u16x8*)dst = o0;
        *(u16x8*)(dst + 8) = o1;
    }
}

// ---------------------------------------------------------------------------
// 8-phase GEMM. C[M,N] = act(A[M,K] @ Bt[N,K]^T + bias (+add)). BM=256, BK=64.
// 512 threads (8 waves). BN=256: 2Mx4N waves; BN=128: 4Mx2N waves.
// LDS: ring of 4 K-half slots per matrix, [rows][32] with XOR'd 16B granules.
// ---------------------------------------------------------------------------
template<int BN, int ACT, bool HAS_ADD, bool OUT_BF>
__global__ __launch_bounds__(512, 1)
void gemm_ph8_k(const unsigned short* __restrict__ A, const unsigned short* __restrict__ Bt,
                const float* __restrict__ bias, const float* __restrict__ add,
                void* __restrict__ Cv, int M, int N, int K)
{
    extern __shared__ __align__(16) unsigned short lds[];
    constexpr int BM = 256;
    constexpr int WN = (BN == 256) ? 4 : 2;
    constexpr int WM = 8 / WN;                 // 2 or 4
    constexpr int WROWS = BM / WM;             // 128 or 64
    constexpr int WCOLS = BN / WN;             // 64
    constexpr int MREP = WROWS / 16;           // 8 or 4
    constexpr int ASLOT = BM * 32;             // 8192 shorts
    constexpr int BSLOT = BN * 32;             // 8192 or 4096 shorts

    const int tid = threadIdx.x;
    const int lane = tid & 63;
    const int w = tid >> 6;
    const int wr = w / WN;
    const int wc = w % WN;
    const int m0 = blockIdx.y * BM;
    const int n0 = blockIdx.x * BN;
    const int fr = lane & 15;
    const int fo = lane >> 4;
    // swizzled fragment 16B-granule within row (per-lane const):
    const int fo_swz8 = (fo ^ ((fr >> 1) & 3)) * 8;

    const int srow = lane >> 2;        // 0..15
    // pre-swizzled source granule: LDS slot (lane&3) holds global granule
    // (lane&3) ^ ((srow>>1)&3); (srow>>1)&3 == (lane>>3)&3. Also valid for
    // rows +16 since (r+16)>>1 & 3 is unchanged.
    const int sswz8 = ((lane & 3) ^ ((lane >> 3) & 3)) * 8;

    f32x4 acc[MREP][4] = {};

    auto stA = [&](int t, int kh) {
        unsigned short* dst = lds + ((2 * t + kh) & 3) * ASLOT + (w * 32) * 32;
        const unsigned short* src = A + (size_t)(m0 + w * 32 + srow) * K + t * 64 + kh * 32 + sswz8;
        GLDS16(src, dst);
        GLDS16(src + (size_t)16 * K, dst + 16 * 32);
    };
    auto stB = [&](int t, int kh) {
        unsigned short* base = lds + 4 * ASLOT + ((2 * t + kh) & 3) * BSLOT;
        if constexpr (BN == 256) {
            unsigned short* dst = base + (w * 32) * 32;
            const unsigned short* src = Bt + (size_t)(n0 + w * 32 + srow) * K + t * 64 + kh * 32 + sswz8;
            GLDS16(src, dst);
            GLDS16(src + (size_t)16 * K, dst + 16 * 32);
        } else {
            unsigned short* dst = base + (w * 16) * 32;
            const unsigned short* src = Bt + (size_t)(n0 + w * 16 + srow) * K + t * 64 + kh * 32 + sswz8;
            GLDS16(src, dst);
        }
    };

    const int NT = K / 64;
    stA(0, 0); stB(0, 0);
    stA(0, 1); stB(0, 1);
    stA(1, 0); stB(1, 0);
    if constexpr (BN == 256) vmwait<8>(); else vmwait<6>();
    BAR();

    for (int t = 0; t < NT; ++t) {
        const bool s1 = (t + 1 < NT);
        const bool s2 = (t + 2 < NT);
        const int tail = (t == NT - 1) ? 2 : ((t == NT - 2) ? 1 : 0);
        const int sl0 = (2 * t) & 3;
        const int sl1 = (2 * t + 1) & 3;

        if constexpr (BN == 256) {
            s16x8 afr[4], bfr[4];
            // ---- p0: mh0 kk0
#pragma unroll
            for (int i = 0; i < 4; ++i)
                afr[i] = *(const s16x8*)(lds + sl0 * ASLOT + (wr * 128 + i * 16 + fr) * 32 + fo_swz8);
#pragma unroll
            for (int j = 0; j < 4; ++j)
                bfr[j] = *(const s16x8*)(lds + 4 * ASLOT + sl0 * BSLOT + (wc * 64 + j * 16 + fr) * 32 + fo_swz8);
            if (s1) stA(t + 1, 1);
            BAR(); LGKM0();
            __builtin_amdgcn_s_setprio(1);
#pragma unroll
            for (int i = 0; i < 4; ++i)
#pragma unroll
                for (int j = 0; j < 4; ++j)
                    acc[i][j] = MFMA16(afr[i], bfr[j], acc[i][j]);
            __builtin_amdgcn_s_setprio(0);
            BAR();
            // ---- p1: mh1 kk0 (reuse B)
#pragma unroll
            for (int i = 0; i < 4; ++i)
                afr[i] = *(const s16x8*)(lds + sl0 * ASLOT + (wr * 128 + 64 + i * 16 + fr) * 32 + fo_swz8);
            if (s1) stB(t + 1, 1);
            BAR(); LGKM0();
            __builtin_amdgcn_s_setprio(1);
#pragma unroll
            for (int i = 0; i < 4; ++i)
#pragma unroll
                for (int j = 0; j < 4; ++j)
                    acc[4 + i][j] = MFMA16(afr[i], bfr[j], acc[4 + i][j]);
            __builtin_amdgcn_s_setprio(0);
            if (tail < 2) vmwait<8>(); else vmwait<0>();
            BAR();
            // ---- p2: mh1 kk1
#pragma unroll
            for (int i = 0; i < 4; ++i)
                afr[i] = *(const s16x8*)(lds + sl1 * ASLOT + (wr * 128 + 64 + i * 16 + fr) * 32 + fo_swz8);
#pragma unroll
            for (int j = 0; j < 4; ++j)
                bfr[j] = *(const s16x8*)(lds + 4 * ASLOT + sl1 * BSLOT + (wc * 64 + j * 16 + fr) * 32 + fo_swz8);
            if (s2) stA(t + 2, 0);
            BAR(); LGKM0();
            __builtin_amdgcn_s_setprio(1);
#pragma unroll
            for (int i = 0; i < 4; ++i)
#pragma unroll
                for (int j = 0; j < 4; ++j)
                    acc[4 + i][j] = MFMA16(afr[i], bfr[j], acc[4 + i][j]);
            __builtin_amdgcn_s_setprio(0);
            BAR();
            // ---- p3: mh0 kk1
#pragma unroll
            for (int i = 0; i < 4; ++i)
                afr[i] = *(const s16x8*)(lds + sl1 * ASLOT + (wr * 128 + i * 16 + fr) * 32 + fo_swz8);
            if (s2) stB(t + 2, 0);
            BAR(); LGKM0();
            __builtin_amdgcn_s_setprio(1);
#pragma unroll
            for (int i = 0; i < 4; ++i)
#pragma unroll
                for (int j = 0; j < 4; ++j)
                    acc[i][j] = MFMA16(afr[i], bfr[j], acc[i][j]);
            __builtin_amdgcn_s_setprio(0);
            if (tail == 0) vmwait<8>(); else if (tail == 1) vmwait<4>();
            BAR();
        } else {
            s16x8 afr[4], bfr[4];
            // ---- p0: kk0
#pragma unroll
            for (int i = 0; i < 4; ++i)
                afr[i] = *(const s16x8*)(lds + sl0 * ASLOT + (wr * 64 + i * 16 + fr) * 32 + fo_swz8);
#pragma unroll
            for (int j = 0; j < 4; ++j)
                bfr[j] = *(const s16x8*)(lds + 4 * ASLOT + sl0 * BSLOT + (wc * 64 + j * 16 + fr) * 32 + fo_swz8);
            if (s1) { stA(t + 1, 1); stB(t + 1, 1); }
            BAR(); LGKM0();
            __builtin_amdgcn_s_setprio(1);
#pragma unroll
            for (int i = 0; i < 4; ++i)
#pragma unroll
                for (int j = 0; j < 4; ++j)
                    acc[i][j] = MFMA16(afr[i], bfr[j], acc[i][j]);
            __builtin_amdgcn_s_setprio(0);
            if (tail < 2) vmwait<6>(); else vmwait<0>();
            BAR();
            // ---- p1: kk1
#pragma unroll
            for (int i = 0; i < 4; ++i)
                afr[i] = *(const s16x8*)(lds + sl1 * ASLOT + (wr * 64 + i * 16 + fr) * 32 + fo_swz8);
#pragma unroll
            for (int j = 0; j < 4; ++j)
                bfr[j] = *(const s16x8*)(lds + 4 * ASLOT + sl1 * BSLOT + (wc * 64 + j * 16 + fr) * 32 + fo_swz8);
            if (s2) { stA(t + 2, 0); stB(t + 2, 0); }
            BAR(); LGKM0();
            __builtin_amdgcn_s_setprio(1);
#pragma unroll
            for (int i = 0; i < 4; ++i)
#pragma unroll
                for (int j = 0; j < 4; ++j)
                    acc[i][j] = MFMA16(afr[i], bfr[j], acc[i][j]);
            __builtin_amdgcn_s_setprio(0);
            if (tail == 0) vmwait<6>(); else if (tail == 1) vmwait<3>();
            BAR();
        }
    }

    // ---- epilogue
    float bv[4];
#pragma unroll
    for (int j = 0; j < 4; ++j)
        bv[j] = bias[n0 + wc * WCOLS + j * 16 + fr];
#pragma unroll
    for (int i = 0; i < MREP; ++i) {
        const int rbase = (BN == 256) ? ((i >> 2) * 64 + (i & 3) * 16) : (i * 16);
#pragma unroll
        for (int j = 0; j < 4; ++j) {
            const int gn = n0 + wc * WCOLS + j * 16 + fr;
#pragma unroll
            for (int r = 0; r < 4; ++r) {
                const int gm = m0 + wr * WROWS + rbase + fo * 4 + r;
                float t = acc[i][j][r] + bv[j];
                if (HAS_ADD) t += add[(size_t)gm * N + gn];
                if (ACT == ACT_GELU)      t = gelu_f(t);
                else if (ACT == ACT_RELU) t = fmaxf(t, 0.f);
                else if (ACT == ACT_SIG)  t = 1.f / (1.f + __expf(-t));
                if (OUT_BF) ((unsigned short*)Cv)[(size_t)gm * N + gn] = f2bf(t);
                else        ((float*)Cv)[(size_t)gm * N + gn] = t;
            }
        }
    }
}

// ---------------------------------------------------------------------------
// Old 2-phase 128x128 GEMM (kept for gate1 N=512 only).
// ---------------------------------------------------------------------------
template<int BM, int BN, int ACT, bool HAS_ADD, bool OUT_BF>
__global__ __launch_bounds__(512, (BM == 128) ? 4 : 2)
void gemm8_k(const unsigned short* __restrict__ A, const unsigned short* __restrict__ Bt,
             const float* __restrict__ bias, const float* __restrict__ add,
             void* __restrict__ Cv, int M, int N, int K)
{
    extern __shared__ __align__(16) unsigned short lds[];
    constexpr int BK = 64;
    constexpr int WN = 2;
    constexpr int WM = 4;
    constexpr int MREP = BM / (WM * 16);
    constexpr int NREP = BN / (WN * 16);
    constexpr int ASZ = BM * BK;
    constexpr int BSZ = BN * BK;
    constexpr int AR = BM / 64;
    constexpr int BR = BN / 64;
    constexpr int VM = AR + BR;

    const int tid = threadIdx.x;
    const int lane = tid & 63;
    const int w = tid >> 6;
    const int wr = w / WN;
    const int wc = w % WN;
    const int m0 = blockIdx.y * BM;
    const int n0 = blockIdx.x * BN;
    const int fr = lane & 15;
    const int fo = lane >> 4;

    const int srow = tid >> 3;
    const int sslot = (tid & 7) ^ (srow & 7);
    const size_t a_base = (size_t)(m0 + srow) * K + sslot * 8;
    const size_t b_base = (size_t)(n0 + srow) * K + sslot * 8;

    f32x4 acc[MREP][NREP] = {};

    auto stage = [&](int t) {
        const int buf = t & 1;
        unsigned short* ad = lds + buf * ASZ + w * 512;
        unsigned short* bd = lds + 2 * ASZ + buf * BSZ + w * 512;
        const unsigned short* as_ = A + a_base + (size_t)t * BK;
        const unsigned short* bs_ = Bt + b_base + (size_t)t * BK;
#pragma unroll
        for (int j = 0; j < AR; ++j)
            GLDS16(as_ + (size_t)j * 64 * K, ad + j * 4096);
#pragma unroll
        for (int j = 0; j < BR; ++j)
            GLDS16(bs_ + (size_t)j * 64 * K, bd + j * 4096);
    };

    const int NT = K / BK;
    stage(0);

    for (int t = 0; t < NT; ++t) {
        if (t + 1 < NT) {
            stage(t + 1);
            asm volatile("s_waitcnt vmcnt(%0)" :: "i"(VM) : "memory");
        } else {
            asm volatile("s_waitcnt vmcnt(0)" ::: "memory");
        }
        __builtin_amdgcn_s_barrier();

        const char* Ab = (const char*)(lds + (t & 1) * ASZ);
        const char* Bb = (const char*)(lds + 2 * ASZ + (t & 1) * BSZ);

        s16x8 af[MREP / 2][2], bfr[NREP][2];
#pragma unroll
        for (int ph = 0; ph < 2; ++ph) {
#pragma unroll
            for (int i = 0; i < MREP / 2; ++i) {
                const int row = wr * (BM / WM) + (ph * (MREP / 2) + i) * 16 + fr;
                const int sw = (row & 7) << 4;
#pragma unroll
                for (int kk = 0; kk < 2; ++kk)
                    af[i][kk] = *(const s16x8*)(Ab + row * 128 + ((kk * 64 + fo * 16) ^ sw));
            }
            if (ph == 0) {
#pragma unroll
                for (int j = 0; j < NREP; ++j) {
                    const int row = wc * 64 + j * 16 + fr;
                    const int sw = (row & 7) << 4;
#pragma unroll
                    for (int kk = 0; kk < 2; ++kk)
                        bfr[j][kk] = *(const s16x8*)(Bb + row * 128 + ((kk * 64 + fo * 16) ^ sw));
                }
            }
            __builtin_amdgcn_s_setprio(1);
#pragma unroll
            for (int i = 0; i < MREP / 2; ++i)
#pragma unroll
                for (int j = 0; j < NREP; ++j)
#pragma unroll
                    for (int kk = 0; kk < 2; ++kk)
                        acc[ph * (MREP / 2) + i][j] =
                            MFMA16(af[i][kk], bfr[j][kk], acc[ph * (MREP / 2) + i][j]);
            __builtin_amdgcn_s_setprio(0);
        }
        asm volatile("s_waitcnt lgkmcnt(0)" ::: "memory");
        __builtin_amdgcn_sched_barrier(0);
        __builtin_amdgcn_s_barrier();
    }

    float bv[NREP];
#pragma unroll
    for (int j = 0; j < NREP; ++j)
        bv[j] = bias[n0 + wc * 64 + j * 16 + fr];
#pragma unroll
    for (int i = 0; i < MREP; ++i) {
#pragma unroll
        for (int j = 0; j < NREP; ++j) {
            const int gn = n0 + wc * 64 + j * 16 + fr;
#pragma unroll
            for (int r = 0; r < 4; ++r) {
                const int gm = m0 + wr * (BM / WM) + i * 16 + fo * 4 + r;
                float t = acc[i][j][r] + bv[j];
                if (HAS_ADD) t += add[(size_t)gm * N + gn];
                if (ACT == ACT_GELU)      t = gelu_f(t);
                else if (ACT == ACT_RELU) t = fmaxf(t, 0.f);
                else if (ACT == ACT_SIG)  t = 1.f / (1.f + __expf(-t));
                if (OUT_BF) ((unsigned short*)Cv)[(size_t)gm * N + gn] = f2bf(t);
                else        ((float*)Cv)[(size_t)gm * N + gn] = t;
            }
        }
    }
}

// ---------------------------------------------------------------------------
// MFMA flash attention v3 (round-8, unchanged).
// ---------------------------------------------------------------------------
__global__ __launch_bounds__(512, 6)
void attn_k(const unsigned short* __restrict__ QKVb, const unsigned short* __restrict__ Vtb,
            unsigned short* __restrict__ Cb)
{
    __shared__ alignas(16) unsigned short Ks[2][64 * 64];
    __shared__ alignas(16) unsigned short Vs[2][64 * 64];
    __shared__ alignas(16) unsigned short Ps[8][16 * 72];

    const int tid = threadIdx.x;
    const int lane = tid & 63;
    const int wid = tid >> 6;
    const int L = blockIdx.x;
    const int xcd = L & 7, s = L >> 3;
    const int bh = xcd + ((s >> 3) << 3);
    const int qt = s & 7;
    const int b = bh >> 4, h = bh & 15;
    const int q0 = qt * 128 + wid * 16;

    const int kcol = lane & 15;
    const int kofs = (lane >> 4) * 8;
    const size_t qoff = ((size_t)(b * NSEQ + q0 + kcol)) * QKVSTR + h * DHEAD + kofs;
    const s16x8 qf0 = *(const s16x8*)(QKVb + qoff);
    const s16x8 qf1 = *(const s16x8*)(QKVb + qoff + 32);

    f32x4 accO[4] = {};
    float mrow[4] = {-1e30f, -1e30f, -1e30f, -1e30f};
    float lsum[4] = {0.f, 0.f, 0.f, 0.f};

    const int lr = lane >> 3;
    const int swz8 = (((lane & 7) ^ lr)) * 8;
    const size_t kbase  = ((size_t)(b * NSEQ)) * QKVSTR + HDIM + h * DHEAD;
    const size_t vtbase = ((size_t)(bh * DHEAD)) * NSEQ;

    unsigned short* const pw = &Ps[wid][0];
    const int prow = (lane >> 4) * 4;

    auto stage = [&](int kt, int buf) {
        const int rowb = wid * 8;
        GLDS16(QKVb + kbase + (size_t)(kt * 64 + rowb + lr) * QKVSTR + swz8,
               Ks[buf] + rowb * 64);
        GLDS16(Vtb + vtbase + (size_t)(rowb + lr) * NSEQ + kt * 64 + swz8,
               Vs[buf] + rowb * 64);
    };

    stage(0, 0);
    asm volatile("s_waitcnt vmcnt(0)" ::: "memory");
    __syncthreads();

    for (int kt = 0; kt < NSEQ / 64; ++kt) {
        const int cur = kt & 1;
        if (kt + 1 < NSEQ / 64) stage(kt + 1, cur ^ 1);

        f32x4 sa[4];
#pragma unroll
        for (int jt = 0; jt < 4; ++jt) {
            const int kr = jt * 16 + kcol;
            const unsigned swz = ((unsigned)(kr & 7)) << 4;
            const s16x8 kf0 = *(const s16x8*)((const char*)Ks[cur] + kr * 128 + ((kofs * 2) ^ swz));
            const s16x8 kf1 = *(const s16x8*)((const char*)Ks[cur] + kr * 128 + ((64 + kofs * 2) ^ swz));
            f32x4 t = {};
            t = MFMA16(qf0, kf0, t);
            t = MFMA16(qf1, kf1, t);
            sa[jt] = t * LOG2E_8;
        }

        float lmax[4];
#pragma unroll
        for (int r = 0; r < 4; ++r)
            lmax[r] = fmaxf(fmaxf(sa[0][r], sa[1][r]), fmaxf(sa[2][r], sa[3][r]));
        const float guard = fmaxf(fmaxf(lmax[0] - mrow[0], lmax[1] - mrow[1]),
                                  fmaxf(lmax[2] - mrow[2], lmax[3] - mrow[3]));
        if (!__all(guard <= 8.f)) {
#pragma unroll
            for (int r = 0; r < 4; ++r) {
                float m = lmax[r];
                m = fmaxf(m, __shfl_xor(m, 1));
                m = fmaxf(m, __shfl_xor(m, 2));
                m = fmaxf(m, __shfl_xor(m, 4));
                m = fmaxf(m, __shfl_xor(m, 8));
                const float mn = fmaxf(mrow[r], m);
                const float corr = exp2f(mrow[r] - mn);
                mrow[r] = mn;
                lsum[r] *= corr;
#pragma unroll
                for (int dt = 0; dt < 4; ++dt) accO[dt][r] *= corr;
            }
        }
#pragma unroll
        for (int r = 0; r < 4; ++r) {
#pragma unroll
            for (int jt = 0; jt < 4; ++jt) {
                const float p = exp2f(sa[jt][r] - mrow[r]);
                pw[(prow + r) * 72 + jt * 16 + kcol] = f2bf(p);
                lsum[r] += p;
            }
        }

#pragma unroll
        for (int kc = 0; kc < 2; ++kc) {
            const s16x8 pa = *(const s16x8*)(pw + kcol * 72 + kc * 32 + kofs);
#pragma unroll
            for (int dt = 0; dt < 4; ++dt) {
                const int dr = dt * 16 + kcol;
                const unsigned swz = ((unsigned)(dr & 7)) << 4;
                const s16x8 vf = *(const s16x8*)((const char*)Vs[cur] + dr * 128 +
                                                 ((kc * 64 + kofs * 2) ^ swz));
                accO[dt] = MFMA16(pa, vf, accO[dt]);
            }
        }

        if (kt + 1 < NSEQ / 64) asm volatile("s_waitcnt vmcnt(0)" ::: "memory");
        __builtin_amdgcn_s_barrier();
    }

#pragma unroll
    for (int r = 0; r < 4; ++r) {
        lsum[r] += __shfl_xor(lsum[r], 1);
        lsum[r] += __shfl_xor(lsum[r], 2);
        lsum[r] += __shfl_xor(lsum[r], 4);
        lsum[r] += __shfl_xor(lsum[r], 8);
    }

    const size_t obase = ((size_t)(b * NSEQ + q0 + prow)) * HDIM + h * DHEAD;
#pragma unroll
    for (int r = 0; r < 4; ++r) {
        const float rl = 1.f / lsum[r];
#pragma unroll
        for (int dt = 0; dt < 4; ++dt)
            Cb[obase + (size_t)r * HDIM + dt * 16 + kcol] = f2bf(accO[dt][r] * rl);
    }
}

// ---------------------------------------------------------------------------
// ada-LayerNorm (unchanged)
// ---------------------------------------------------------------------------
template<int MODE, bool WRITE_BF>
__global__ __launch_bounds__(256)
void adaln_k(const float* __restrict__ a, const float* __restrict__ fo,
             const float* __restrict__ g, const float* __restrict__ vol,
             const float* __restrict__ lw, const float* __restrict__ lb,
             const float* __restrict__ gm, const float* __restrict__ bt,
             const float* __restrict__ vsw, const float* __restrict__ vsb,
             float* __restrict__ out, unsigned short* __restrict__ out_bf)
{
    const int tok = blockIdx.x;
    const int tid = threadIdx.x;
    const size_t base = (size_t)tok * HDIM + tid * 4;
    float v[4];
    {
        float4 va = *(const float4*)&a[base];
        if (MODE == 1) {
            float4 vf = *(const float4*)&fo[base];
            float4 vg = *(const float4*)&g[base];
            v[0] = va.x * (2.f - vg.x) + vf.x * vg.x;
            v[1] = va.y * (2.f - vg.y) + vf.y * vg.y;
            v[2] = va.z * (2.f - vg.z) + vf.z * vg.z;
            v[3] = va.w * (2.f - vg.w) + vf.w * vg.w;
        } else {
            v[0] = va.x; v[1] = va.y; v[2] = va.z; v[3] = va.w;
        }
    }
    float sum = v[0] + v[1] + v[2] + v[3];
    float sq  = v[0]*v[0] + v[1]*v[1] + v[2]*v[2] + v[3]*v[3];
#pragma unroll
    for (int off = 32; off > 0; off >>= 1) {
        sum += __shfl_down(sum, off);
        sq  += __shfl_down(sq, off);
    }
    __shared__ float ssum[4], ssq[4];
    const int wid = tid >> 6, lane = tid & 63;
    if (lane == 0) { ssum[wid] = sum; ssq[wid] = sq; }
    __syncthreads();
    const float tsum = ssum[0] + ssum[1] + ssum[2] + ssum[3];
    const float tsq  = ssq[0]  + ssq[1]  + ssq[2]  + ssq[3];
    const float mu   = tsum * (1.f / 1024.f);
    const float var  = tsq * (1.f / 1024.f) - mu * mu;
    const float rstd = rsqrtf(var + LNEPS);
    const float vsv  = 1.f / (1.f + __expf(-(vol[tok] * vsw[0] + vsb[0])));
    const float sca  = (1.f + vsv) * gm[0];
    const float off2 = bt[0];
    const float4 lwv = *(const float4*)&lw[tid * 4];
    const float4 lbv = *(const float4*)&lb[tid * 4];
    float r0 = ((v[0] - mu) * rstd * lwv.x + lbv.x) * sca + off2;
    float r1 = ((v[1] - mu) * rstd * lwv.y + lbv.y) * sca + off2;
    float r2 = ((v[2] - mu) * rstd * lwv.z + lbv.z) * sca + off2;
    float r3 = ((v[3] - mu) * rstd * lwv.w + lbv.w) * sca + off2;
    *(float4*)&out[base] = make_float4(r0, r1, r2, r3);
    if (WRITE_BF) {
        ushort4 ob;
        ob.x = f2bf(r0); ob.y = f2bf(r1); ob.z = f2bf(r2); ob.w = f2bf(r3);
        *(ushort4*)&out_bf[base] = ob;
    }
}

// ---------------------------------------------------------------------------
extern "C" void kernel_launch(void* const* d_in, const int* in_sizes, int n_in,
                              void* d_out, int out_size, void* d_ws, size_t ws_size,
                              hipStream_t stream)
{
    (void)in_sizes; (void)n_in; (void)out_size; (void)ws_size;
    const float* x    = (const float*)d_in[0];
    const float* vol  = (const float*)d_in[1];
    const float* Wq   = (const float*)d_in[2];  const float* bq  = (const float*)d_in[3];
    const float* Wk   = (const float*)d_in[4];  const float* bk  = (const float*)d_in[5];
    const float* Wv   = (const float*)d_in[6];  const float* bv  = (const float*)d_in[7];
    const float* Wo   = (const float*)d_in[8];  const float* bo  = (const float*)d_in[9];
    const float* ln1w = (const float*)d_in[10]; const float* ln1b = (const float*)d_in[11];
    const float* gm1  = (const float*)d_in[12]; const float* be1 = (const float*)d_in[13];
    const float* vs1w = (const float*)d_in[14]; const float* vs1b = (const float*)d_in[15];
    const float* fw1  = (const float*)d_in[16]; const float* fb1 = (const float*)d_in[17];
    const float* fw2  = (const float*)d_in[18]; const float* fb2 = (const float*)d_in[19];
    const float* gw1  = (const float*)d_in[20]; const float* gb1 = (const float*)d_in[21];
    const float* gw2  = (const float*)d_in[22]; const float* gb2 = (const float*)d_in[23];
    const float* ln2w = (const float*)d_in[24]; const float* ln2b = (const float*)d_in[25];
    const float* gm2  = (const float*)d_in[26]; const float* be2 = (const float*)d_in[27];
    const float* vs2w = (const float*)d_in[28]; const float* vs2b = (const float*)d_in[29];

    char* w = (char*)d_ws;
    auto MB = [](size_t v) { return v << 20; };
    unsigned short* wtqkv = (unsigned short*)(w + MB(0));   // 0-6
    unsigned short* wto   = (unsigned short*)(w + MB(6));
    unsigned short* wtf1  = (unsigned short*)(w + MB(8));
    unsigned short* wtf2  = (unsigned short*)(w + MB(16));
    unsigned short* wtg1  = (unsigned short*)(w + MB(24));
    unsigned short* wtg2  = (unsigned short*)(w + MB(25));
    unsigned short* xb   = (unsigned short*)(w + MB(26));   // 26-42
    unsigned short* qkvb = (unsigned short*)(w + MB(42));   // 42-90
    unsigned short* vtb  = (unsigned short*)(w + MB(90));   // 90-106
    unsigned short* cxb  = (unsigned short*)(w + MB(106));  // 106-122
    float*          ao   = (float*)(w + MB(122));           // 122-154
    float*          x1   = (float*)(w + MB(42));            // 42-74 (qkv dead)
    unsigned short* x1b  = (unsigned short*)(w + MB(74));   // 74-90
    unsigned short* hb   = (unsigned short*)(w + MB(90));   // 90-154
    float*          ffn  = (float*)(w + MB(154));           // 154-186
    unsigned short* ghb  = (unsigned short*)(w + MB(26));   // 26-34 (xb dead)
    float*          gg   = (float*)(w + MB(90));            // 90-122 (hb dead)
    float*          bqkv = (float*)(w + MB(186));

    dim3 blk(256);
    dim3 tb(32, 8);
    transpose_cast4_k<<<dim3(32, 32, 4), tb, 0, stream>>>(Wq, Wk, Wv, Wo, wtqkv);
    transpose_cast_k<<<dim3(4096/32, 1024/32), tb, 0, stream>>>(fw1, wtf1, 1024, 4096);
    transpose_cast_k<<<dim3(1024/32, 4096/32), tb, 0, stream>>>(fw2, wtf2, 4096, 1024);
    transpose_cast_k<<<dim3(512/32, 1024/32),  tb, 0, stream>>>(gw1, wtg1, 1024, 512);
    transpose_cast_k<<<dim3(1024/32, 512/32),  tb, 0, stream>>>(gw2, wtg2, 512, 1024);
    cast_bf16_k<<<2048, blk, 0, stream>>>(x, xb, NTOK * HDIM / 4);
    concat3_k<<<12, blk, 0, stream>>>(bq, bk, bv, bqkv);

    const size_t PH256 = 131072;
    const size_t PH128 = 98304;
    const size_t SH128 = (128 + 128) * 256;

    gemm_ph8_k<128, ACT_NONE, false, true><<<dim3(24, 32), 512, PH128, stream>>>(
        xb, wtqkv, bqkv, nullptr, qkvb, NTOK, QKVSTR, HDIM);
    transpose_v_k<<<dim3(NSEQ / 64, NHEAD, NBATCH), blk, 0, stream>>>(qkvb + 2048, vtb);
    attn_k<<<dim3(1024), 512, 0, stream>>>(qkvb, vtb, cxb);
    gemm_ph8_k<128, ACT_NONE, true, false><<<dim3(8, 32), 512, PH128, stream>>>(
        cxb, wto, bo, x, ao, NTOK, HDIM, HDIM);
    adaln_k<0, true><<<dim3(NTOK), blk, 0, stream>>>(
        ao, nullptr, nullptr, vol, ln1w, ln1b, gm1, be1, vs1w, vs1b, x1, x1b);
    gemm_ph8_k<256, ACT_GELU, false, true><<<dim3(16, 32), 512, PH256, stream>>>(
        x1b, wtf1, fb1, nullptr, hb, NTOK, 4096, HDIM);
    gemm_ph8_k<128, ACT_NONE, false, false><<<dim3(8, 32), 512, PH128, stream>>>(
        hb, wtf2, fb2, nullptr, ffn, NTOK, HDIM, 4096);
    gemm8_k<128, 128, ACT_RELU, false, true><<<dim3(4, 64), 512, SH128, stream>>>(
        x1b, wtg1, gb1, nullptr, ghb, NTOK, 512, HDIM);
    gemm_ph8_k<128, ACT_SIG, false, false><<<dim3(8, 32), 512, PH128, stream>>>(
        ghb, wtg2, gb2, nullptr, gg, NTOK, HDIM, 512);
    adaln_k<1, false><<<dim3(NTOK), blk, 0, stream>>>(
        x1, ffn, gg, vol, ln2w, ln2b, gm2, be2, vs2w, vs2b, (float*)d_out, nullptr);
}

// Round 11
// 469.385 us; speedup vs baseline: 1.0475x; 1.0147x over previous
//
#include <hip/hip_runtime.h>
#include <hip/hip_bf16.h>
#include <math.h>

// EnhancedTransformerBlock on MI355X — Round 11: high-occupancy GEMM.
// Lesson from R5-R10: every deep schedule at 1 block/CU (2 waves/SIMD) is stuck
// at ~21% MfmaUtil — stalls have nothing to fill them. m97/m114 evidence: plain
// 2-barrier loop at multiple blocks/CU wins via cross-block TLP.
// New gemm_hi_k: 256 thr (4 waves 2x2), 128x128 tile, BK=32, static 32 KiB LDS
// dbuf, R10-proven granule-XOR swizzle (0 conflicts), counted vmcnt(4),
// launch_bounds(256,4) -> 4 blocks/CU = 16 waves/CU. XCD-chunked block swizzle.
// attn v3 / adaLN / preps unchanged from round 8/10.

#define HDIM 1024
#define NHEAD 16
#define DHEAD 64
#define NBATCH 8
#define NSEQ 1024
#define NTOK (NBATCH * NSEQ)   // 8192
#define QKVSTR 3072
#define LNEPS 1e-5f
#define LOG2E_8 0.180336880f   // log2(e)/8

using f32x4 = __attribute__((ext_vector_type(4))) float;
using s16x8 = __attribute__((ext_vector_type(8))) short;
using u16x8 = __attribute__((ext_vector_type(8))) unsigned short;

enum { ACT_NONE = 0, ACT_GELU = 1, ACT_RELU = 2, ACT_SIG = 3 };

__device__ inline float bf2f(unsigned short u) {
    union { unsigned u; float f; } t; t.u = ((unsigned)u) << 16; return t.f;
}
__device__ inline unsigned short f2bf(float f) {
    __hip_bfloat16 h = __float2bfloat16(f);
    return *reinterpret_cast<unsigned short*>(&h);
}
__device__ inline float gelu_f(float t) {
    const float u = t * (0.7978845608f + 0.0356774081f * t * t);
    const float e = __expf(2.f * u);
    const float th = 1.f - 2.f / (e + 1.f);
    return 0.5f * t * (1.f + th);
}

#define GLDS16(g, l) __builtin_amdgcn_global_load_lds( \
    (__attribute__((address_space(1))) void*)(g),      \
    (__attribute__((address_space(3))) void*)(l), 16, 0, 0)
#define MFMA16(a, b, c) __builtin_amdgcn_mfma_f32_16x16x32_bf16(a, b, c, 0, 0, 0)
#define BAR() __builtin_amdgcn_s_barrier()
#define LGKM0() do { asm volatile("s_waitcnt lgkmcnt(0)" ::: "memory"); \
                     __builtin_amdgcn_sched_barrier(0); } while (0)

template<int N> __device__ __forceinline__ void vmwait() {
    asm volatile("s_waitcnt vmcnt(%0)" :: "i"(N) : "memory");
}

// ---------------------------------------------------------------------------
__global__ __launch_bounds__(256)
void cast_bf16_k(const float* __restrict__ in, unsigned short* __restrict__ out, int n4)
{
    for (int i = blockIdx.x * 256 + threadIdx.x; i < n4; i += gridDim.x * 256) {
        float4 v = ((const float4*)in)[i];
        ushort4 o;
        o.x = f2bf(v.x); o.y = f2bf(v.y); o.z = f2bf(v.z); o.w = f2bf(v.w);
        ((ushort4*)out)[i] = o;
    }
}

// ---------------------------------------------------------------------------
__global__ __launch_bounds__(256)
void concat3_k(const float* __restrict__ a, const float* __restrict__ b,
               const float* __restrict__ c, float* __restrict__ o)
{
    int i = blockIdx.x * 256 + threadIdx.x;
    o[i] = i < 1024 ? a[i] : (i < 2048 ? b[i - 1024] : c[i - 2048]);
}

// ---------------------------------------------------------------------------
__global__ __launch_bounds__(256)
void transpose_cast_k(const float* __restrict__ W, unsigned short* __restrict__ Wt,
                      int K, int N)
{
    __shared__ float tile[32][33];
    const int tx = threadIdx.x, ty = threadIdx.y;
    const int k0 = blockIdx.y * 32, n0 = blockIdx.x * 32;
#pragma unroll
    for (int r = 0; r < 32; r += 8)
        tile[ty + r][tx] = W[(size_t)(k0 + ty + r) * N + n0 + tx];
    __syncthreads();
#pragma unroll
    for (int r = 0; r < 32; r += 8)
        Wt[(size_t)(n0 + ty + r) * K + k0 + tx] = f2bf(tile[tx][ty + r]);
}

__global__ __launch_bounds__(256)
void transpose_cast4_k(const float* __restrict__ W0, const float* __restrict__ W1,
                       const float* __restrict__ W2, const float* __restrict__ W3,
                       unsigned short* __restrict__ Wt)
{
    __shared__ float tile[32][33];
    const int z = blockIdx.z;
    const float* W = z == 0 ? W0 : z == 1 ? W1 : z == 2 ? W2 : W3;
    unsigned short* dst = Wt + (size_t)z * HDIM * HDIM;
    const int tx = threadIdx.x, ty = threadIdx.y;
    const int k0 = blockIdx.y * 32, n0 = blockIdx.x * 32;
#pragma unroll
    for (int r = 0; r < 32; r += 8)
        tile[ty + r][tx] = W[(size_t)(k0 + ty + r) * HDIM + n0 + tx];
    __syncthreads();
#pragma unroll
    for (int r = 0; r < 32; r += 8)
        dst[(size_t)(n0 + ty + r) * HDIM + k0 + tx] = f2bf(tile[tx][ty + r]);
}

// ---------------------------------------------------------------------------
__global__ __launch_bounds__(256)
void transpose_v_k(const unsigned short* __restrict__ vb, unsigned short* __restrict__ vtb)
{
    __shared__ unsigned short t[64][72];
    const int tid = threadIdx.x;
    const int b = blockIdx.z, h = blockIdx.y;
    const int s0 = blockIdx.x * 64;
    {
        const int r = tid >> 3, c = (tid & 7) * 8;
        *(u16x8*)&t[r][c] =
            *(const u16x8*)&vb[((size_t)(b * NSEQ + s0 + r)) * QKVSTR + h * DHEAD + c];
        *(u16x8*)&t[r + 32][c] =
            *(const u16x8*)&vb[((size_t)(b * NSEQ + s0 + r + 32)) * QKVSTR + h * DHEAD + c];
    }
    __syncthreads();
    {
        const int d = tid & 63, sc = (tid >> 6) * 16;
        u16x8 o0, o1;
#pragma unroll
        for (int i = 0; i < 8; ++i) o0[i] = t[sc + i][d];
#pragma unroll
        for (int i = 0; i < 8; ++i) o1[i] = t[sc + 8 + i][d];
        unsigned short* dst = &vtb[((size_t)((b * NHEAD + h) * DHEAD + d)) * NSEQ + s0 + sc];
        *(u16x8*)dst = o0;
        *(u16x8*)(dst + 8) = o1;
    }
}

// ---------------------------------------------------------------------------
// High-occupancy GEMM: C[M,N] = act(A[M,K] @ Bt[N,K]^T + bias (+add)).
// 128x128 tile, BK=32, 256 threads (4 waves 2x2), static 32 KiB LDS dbuf,
// granule-XOR swizzle (R10-proven, 0 conflicts), counted vmcnt(4).
// 4 blocks/CU. Grid 1D (nbx*nby), XCD-chunked swizzle (total % 8 == 0).
// ---------------------------------------------------------------------------
template<int ACT, bool HAS_ADD, bool OUT_BF>
__global__ __launch_bounds__(256, 4)
void gemm_hi_k(const unsigned short* __restrict__ A, const unsigned short* __restrict__ Bt,
               const float* __restrict__ bias, const float* __restrict__ add,
               void* __restrict__ Cv, int M, int N, int K, int nbx)
{
    __shared__ alignas(16) unsigned short As[2][128 * 32];
    __shared__ alignas(16) unsigned short Bs[2][128 * 32];

    const int tid = threadIdx.x;
    const int lane = tid & 63;
    const int w = tid >> 6;            // 0..3
    const int wr = w >> 1, wc = w & 1; // 2x2 wave grid
    // XCD-chunked bijective swizzle (gridDim.x % 8 == 0 by construction)
    const int chunk = gridDim.x >> 3;
    const int wg = (blockIdx.x & 7) * chunk + (blockIdx.x >> 3);
    const int m0 = (wg / nbx) * 128;
    const int n0 = (wg % nbx) * 128;

    const int fr = lane & 15;
    const int fo = lane >> 4;                       // 0..3 k-granule
    const int fo_swz8 = (fo ^ ((fr >> 1) & 3)) * 8; // swizzled read granule

    // staging: thread covers 16B granule (tid&3) of row (tid>>2); source
    // granule pre-swizzled so LDS holds granule g at g ^ ((row>>1)&3).
    const int srow = tid >> 2;                      // 0..63
    const int sg8 = ((tid & 3) ^ ((tid >> 3) & 3)) * 8;

    f32x4 acc[4][4] = {};

    auto stage = [&](int t) {
        const int buf = t & 1;
        const unsigned short* as_ = A + (size_t)(m0 + srow) * K + t * 32 + sg8;
        const unsigned short* bs_ = Bt + (size_t)(n0 + srow) * K + t * 32 + sg8;
        GLDS16(as_, &As[buf][(w * 16) * 32]);
        GLDS16(as_ + (size_t)64 * K, &As[buf][(64 + w * 16) * 32]);
        GLDS16(bs_, &Bs[buf][(w * 16) * 32]);
        GLDS16(bs_ + (size_t)64 * K, &Bs[buf][(64 + w * 16) * 32]);
    };

    const int NT = K / 32;
    stage(0);

    for (int t = 0; t < NT; ++t) {
        if (t + 1 < NT) { stage(t + 1); vmwait<4>(); }
        else            { vmwait<0>(); }
        BAR();

        const int buf = t & 1;
        s16x8 af[4], bf[4];
#pragma unroll
        for (int i = 0; i < 4; ++i)
            af[i] = *(const s16x8*)(&As[buf][(wr * 64 + i * 16 + fr) * 32 + fo_swz8]);
#pragma unroll
        for (int j = 0; j < 4; ++j)
            bf[j] = *(const s16x8*)(&Bs[buf][(wc * 64 + j * 16 + fr) * 32 + fo_swz8]);

        __builtin_amdgcn_s_setprio(1);
#pragma unroll
        for (int i = 0; i < 4; ++i)
#pragma unroll
            for (int j = 0; j < 4; ++j)
                acc[i][j] = MFMA16(af[i], bf[j], acc[i][j]);
        __builtin_amdgcn_s_setprio(0);

        LGKM0();   // all ds_reads done before next overwrite of this buffer
        BAR();
    }

    // epilogue
    float bv[4];
#pragma unroll
    for (int j = 0; j < 4; ++j)
        bv[j] = bias[n0 + wc * 64 + j * 16 + fr];
#pragma unroll
    for (int i = 0; i < 4; ++i) {
#pragma unroll
        for (int j = 0; j < 4; ++j) {
            const int gn = n0 + wc * 64 + j * 16 + fr;
#pragma unroll
            for (int r = 0; r < 4; ++r) {
                const int gm = m0 + wr * 64 + i * 16 + fo * 4 + r;
                float t = acc[i][j][r] + bv[j];
                if (HAS_ADD) t += add[(size_t)gm * N + gn];
                if (ACT == ACT_GELU)      t = gelu_f(t);
                else if (ACT == ACT_RELU) t = fmaxf(t, 0.f);
                else if (ACT == ACT_SIG)  t = 1.f / (1.f + __expf(-t));
                if (OUT_BF) ((unsigned short*)Cv)[(size_t)gm * N + gn] = f2bf(t);
                else        ((float*)Cv)[(size_t)gm * N + gn] = t;
            }
        }
    }
}

// ---------------------------------------------------------------------------
// MFMA flash attention v3 (round-8, unchanged).
// ---------------------------------------------------------------------------
__global__ __launch_bounds__(512, 6)
void attn_k(const unsigned short* __restrict__ QKVb, const unsigned short* __restrict__ Vtb,
            unsigned short* __restrict__ Cb)
{
    __shared__ alignas(16) unsigned short Ks[2][64 * 64];
    __shared__ alignas(16) unsigned short Vs[2][64 * 64];
    __shared__ alignas(16) unsigned short Ps[8][16 * 72];

    const int tid = threadIdx.x;
    const int lane = tid & 63;
    const int wid = tid >> 6;
    const int L = blockIdx.x;
    const int xcd = L & 7, s = L >> 3;
    const int bh = xcd + ((s >> 3) << 3);
    const int qt = s & 7;
    const int b = bh >> 4, h = bh & 15;
    const int q0 = qt * 128 + wid * 16;

    const int kcol = lane & 15;
    const int kofs = (lane >> 4) * 8;
    const size_t qoff = ((size_t)(b * NSEQ + q0 + kcol)) * QKVSTR + h * DHEAD + kofs;
    const s16x8 qf0 = *(const s16x8*)(QKVb + qoff);
    const s16x8 qf1 = *(const s16x8*)(QKVb + qoff + 32);

    f32x4 accO[4] = {};
    float mrow[4] = {-1e30f, -1e30f, -1e30f, -1e30f};
    float lsum[4] = {0.f, 0.f, 0.f, 0.f};

    const int lr = lane >> 3;
    const int swz8 = (((lane & 7) ^ lr)) * 8;
    const size_t kbase  = ((size_t)(b * NSEQ)) * QKVSTR + HDIM + h * DHEAD;
    const size_t vtbase = ((size_t)(bh * DHEAD)) * NSEQ;

    unsigned short* const pw = &Ps[wid][0];
    const int prow = (lane >> 4) * 4;

    auto stage = [&](int kt, int buf) {
        const int rowb = wid * 8;
        GLDS16(QKVb + kbase + (size_t)(kt * 64 + rowb + lr) * QKVSTR + swz8,
               Ks[buf] + rowb * 64);
        GLDS16(Vtb + vtbase + (size_t)(rowb + lr) * NSEQ + kt * 64 + swz8,
               Vs[buf] + rowb * 64);
    };

    stage(0, 0);
    asm volatile("s_waitcnt vmcnt(0)" ::: "memory");
    __syncthreads();

    for (int kt = 0; kt < NSEQ / 64; ++kt) {
        const int cur = kt & 1;
        if (kt + 1 < NSEQ / 64) stage(kt + 1, cur ^ 1);

        f32x4 sa[4];
#pragma unroll
        for (int jt = 0; jt < 4; ++jt) {
            const int kr = jt * 16 + kcol;
            const unsigned swz = ((unsigned)(kr & 7)) << 4;
            const s16x8 kf0 = *(const s16x8*)((const char*)Ks[cur] + kr * 128 + ((kofs * 2) ^ swz));
            const s16x8 kf1 = *(const s16x8*)((const char*)Ks[cur] + kr * 128 + ((64 + kofs * 2) ^ swz));
            f32x4 t = {};
            t = MFMA16(qf0, kf0, t);
            t = MFMA16(qf1, kf1, t);
            sa[jt] = t * LOG2E_8;
        }

        float lmax[4];
#pragma unroll
        for (int r = 0; r < 4; ++r)
            lmax[r] = fmaxf(fmaxf(sa[0][r], sa[1][r]), fmaxf(sa[2][r], sa[3][r]));
        const float guard = fmaxf(fmaxf(lmax[0] - mrow[0], lmax[1] - mrow[1]),
                                  fmaxf(lmax[2] - mrow[2], lmax[3] - mrow[3]));
        if (!__all(guard <= 8.f)) {
#pragma unroll
            for (int r = 0; r < 4; ++r) {
                float m = lmax[r];
                m = fmaxf(m, __shfl_xor(m, 1));
                m = fmaxf(m, __shfl_xor(m, 2));
                m = fmaxf(m, __shfl_xor(m, 4));
                m = fmaxf(m, __shfl_xor(m, 8));
                const float mn = fmaxf(mrow[r], m);
                const float corr = exp2f(mrow[r] - mn);
                mrow[r] = mn;
                lsum[r] *= corr;
#pragma unroll
                for (int dt = 0; dt < 4; ++dt) accO[dt][r] *= corr;
            }
        }
#pragma unroll
        for (int r = 0; r < 4; ++r) {
#pragma unroll
            for (int jt = 0; jt < 4; ++jt) {
                const float p = exp2f(sa[jt][r] - mrow[r]);
                pw[(prow + r) * 72 + jt * 16 + kcol] = f2bf(p);
                lsum[r] += p;
            }
        }

#pragma unroll
        for (int kc = 0; kc < 2; ++kc) {
            const s16x8 pa = *(const s16x8*)(pw + kcol * 72 + kc * 32 + kofs);
#pragma unroll
            for (int dt = 0; dt < 4; ++dt) {
                const int dr = dt * 16 + kcol;
                const unsigned swz = ((unsigned)(dr & 7)) << 4;
                const s16x8 vf = *(const s16x8*)((const char*)Vs[cur] + dr * 128 +
                                                 ((kc * 64 + kofs * 2) ^ swz));
                accO[dt] = MFMA16(pa, vf, accO[dt]);
            }
        }

        if (kt + 1 < NSEQ / 64) asm volatile("s_waitcnt vmcnt(0)" ::: "memory");
        __builtin_amdgcn_s_barrier();
    }

#pragma unroll
    for (int r = 0; r < 4; ++r) {
        lsum[r] += __shfl_xor(lsum[r], 1);
        lsum[r] += __shfl_xor(lsum[r], 2);
        lsum[r] += __shfl_xor(lsum[r], 4);
        lsum[r] += __shfl_xor(lsum[r], 8);
    }

    const size_t obase = ((size_t)(b * NSEQ + q0 + prow)) * HDIM + h * DHEAD;
#pragma unroll
    for (int r = 0; r < 4; ++r) {
        const float rl = 1.f / lsum[r];
#pragma unroll
        for (int dt = 0; dt < 4; ++dt)
            Cb[obase + (size_t)r * HDIM + dt * 16 + kcol] = f2bf(accO[dt][r] * rl);
    }
}

// ---------------------------------------------------------------------------
// ada-LayerNorm (unchanged)
// ---------------------------------------------------------------------------
template<int MODE, bool WRITE_BF>
__global__ __launch_bounds__(256)
void adaln_k(const float* __restrict__ a, const float* __restrict__ fo,
             const float* __restrict__ g, const float* __restrict__ vol,
             const float* __restrict__ lw, const float* __restrict__ lb,
             const float* __restrict__ gm, const float* __restrict__ bt,
             const float* __restrict__ vsw, const float* __restrict__ vsb,
             float* __restrict__ out, unsigned short* __restrict__ out_bf)
{
    const int tok = blockIdx.x;
    const int tid = threadIdx.x;
    const size_t base = (size_t)tok * HDIM + tid * 4;
    float v[4];
    {
        float4 va = *(const float4*)&a[base];
        if (MODE == 1) {
            float4 vf = *(const float4*)&fo[base];
            float4 vg = *(const float4*)&g[base];
            v[0] = va.x * (2.f - vg.x) + vf.x * vg.x;
            v[1] = va.y * (2.f - vg.y) + vf.y * vg.y;
            v[2] = va.z * (2.f - vg.z) + vf.z * vg.z;
            v[3] = va.w * (2.f - vg.w) + vf.w * vg.w;
        } else {
            v[0] = va.x; v[1] = va.y; v[2] = va.z; v[3] = va.w;
        }
    }
    float sum = v[0] + v[1] + v[2] + v[3];
    float sq  = v[0]*v[0] + v[1]*v[1] + v[2]*v[2] + v[3]*v[3];
#pragma unroll
    for (int off = 32; off > 0; off >>= 1) {
        sum += __shfl_down(sum, off);
        sq  += __shfl_down(sq, off);
    }
    __shared__ float ssum[4], ssq[4];
    const int wid = tid >> 6, lane = tid & 63;
    if (lane == 0) { ssum[wid] = sum; ssq[wid] = sq; }
    __syncthreads();
    const float tsum = ssum[0] + ssum[1] + ssum[2] + ssum[3];
    const float tsq  = ssq[0]  + ssq[1]  + ssq[2]  + ssq[3];
    const float mu   = tsum * (1.f / 1024.f);
    const float var  = tsq * (1.f / 1024.f) - mu * mu;
    const float rstd = rsqrtf(var + LNEPS);
    const float vsv  = 1.f / (1.f + __expf(-(vol[tok] * vsw[0] + vsb[0])));
    const float sca  = (1.f + vsv) * gm[0];
    const float off2 = bt[0];
    const float4 lwv = *(const float4*)&lw[tid * 4];
    const float4 lbv = *(const float4*)&lb[tid * 4];
    float r0 = ((v[0] - mu) * rstd * lwv.x + lbv.x) * sca + off2;
    float r1 = ((v[1] - mu) * rstd * lwv.y + lbv.y) * sca + off2;
    float r2 = ((v[2] - mu) * rstd * lwv.z + lbv.z) * sca + off2;
    float r3 = ((v[3] - mu) * rstd * lwv.w + lbv.w) * sca + off2;
    *(float4*)&out[base] = make_float4(r0, r1, r2, r3);
    if (WRITE_BF) {
        ushort4 ob;
        ob.x = f2bf(r0); ob.y = f2bf(r1); ob.z = f2bf(r2); ob.w = f2bf(r3);
        *(ushort4*)&out_bf[base] = ob;
    }
}

// ---------------------------------------------------------------------------
extern "C" void kernel_launch(void* const* d_in, const int* in_sizes, int n_in,
                              void* d_out, int out_size, void* d_ws, size_t ws_size,
                              hipStream_t stream)
{
    (void)in_sizes; (void)n_in; (void)out_size; (void)ws_size;
    const float* x    = (const float*)d_in[0];
    const float* vol  = (const float*)d_in[1];
    const float* Wq   = (const float*)d_in[2];  const float* bq  = (const float*)d_in[3];
    const float* Wk   = (const float*)d_in[4];  const float* bk  = (const float*)d_in[5];
    const float* Wv   = (const float*)d_in[6];  const float* bv  = (const float*)d_in[7];
    const float* Wo   = (const float*)d_in[8];  const float* bo  = (const float*)d_in[9];
    const float* ln1w = (const float*)d_in[10]; const float* ln1b = (const float*)d_in[11];
    const float* gm1  = (const float*)d_in[12]; const float* be1 = (const float*)d_in[13];
    const float* vs1w = (const float*)d_in[14]; const float* vs1b = (const float*)d_in[15];
    const float* fw1  = (const float*)d_in[16]; const float* fb1 = (const float*)d_in[17];
    const float* fw2  = (const float*)d_in[18]; const float* fb2 = (const float*)d_in[19];
    const float* gw1  = (const float*)d_in[20]; const float* gb1 = (const float*)d_in[21];
    const float* gw2  = (const float*)d_in[22]; const float* gb2 = (const float*)d_in[23];
    const float* ln2w = (const float*)d_in[24]; const float* ln2b = (const float*)d_in[25];
    const float* gm2  = (const float*)d_in[26]; const float* be2 = (const float*)d_in[27];
    const float* vs2w = (const float*)d_in[28]; const float* vs2b = (const float*)d_in[29];

    char* w = (char*)d_ws;
    auto MB = [](size_t v) { return v << 20; };
    unsigned short* wtqkv = (unsigned short*)(w + MB(0));   // 0-6
    unsigned short* wto   = (unsigned short*)(w + MB(6));
    unsigned short* wtf1  = (unsigned short*)(w + MB(8));
    unsigned short* wtf2  = (unsigned short*)(w + MB(16));
    unsigned short* wtg1  = (unsigned short*)(w + MB(24));
    unsigned short* wtg2  = (unsigned short*)(w + MB(25));
    unsigned short* xb   = (unsigned short*)(w + MB(26));   // 26-42
    unsigned short* qkvb = (unsigned short*)(w + MB(42));   // 42-90
    unsigned short* vtb  = (unsigned short*)(w + MB(90));   // 90-106
    unsigned short* cxb  = (unsigned short*)(w + MB(106));  // 106-122
    float*          ao   = (float*)(w + MB(122));           // 122-154
    float*          x1   = (float*)(w + MB(42));            // 42-74 (qkv dead)
    unsigned short* x1b  = (unsigned short*)(w + MB(74));   // 74-90
    unsigned short* hb   = (unsigned short*)(w + MB(90));   // 90-154
    float*          ffn  = (float*)(w + MB(154));           // 154-186
    unsigned short* ghb  = (unsigned short*)(w + MB(26));   // 26-34 (xb dead)
    float*          gg   = (float*)(w + MB(90));            // 90-122 (hb dead)
    float*          bqkv = (float*)(w + MB(186));

    dim3 blk(256);
    dim3 tb(32, 8);
    transpose_cast4_k<<<dim3(32, 32, 4), tb, 0, stream>>>(Wq, Wk, Wv, Wo, wtqkv);
    transpose_cast_k<<<dim3(4096/32, 1024/32), tb, 0, stream>>>(fw1, wtf1, 1024, 4096);
    transpose_cast_k<<<dim3(1024/32, 4096/32), tb, 0, stream>>>(fw2, wtf2, 4096, 1024);
    transpose_cast_k<<<dim3(512/32, 1024/32),  tb, 0, stream>>>(gw1, wtg1, 1024, 512);
    transpose_cast_k<<<dim3(1024/32, 512/32),  tb, 0, stream>>>(gw2, wtg2, 512, 1024);
    cast_bf16_k<<<2048, blk, 0, stream>>>(x, xb, NTOK * HDIM / 4);
    concat3_k<<<12, blk, 0, stream>>>(bq, bk, bv, bqkv);

    // grids: 1D = nbx * (M/128); all totals divisible by 8 (XCD swizzle).
    gemm_hi_k<ACT_NONE, false, true><<<dim3(24 * 64), blk, 0, stream>>>(
        xb, wtqkv, bqkv, nullptr, qkvb, NTOK, QKVSTR, HDIM, 24);
    transpose_v_k<<<dim3(NSEQ / 64, NHEAD, NBATCH), blk, 0, stream>>>(qkvb + 2048, vtb);
    attn_k<<<dim3(1024), 512, 0, stream>>>(qkvb, vtb, cxb);
    gemm_hi_k<ACT_NONE, true, false><<<dim3(8 * 64), blk, 0, stream>>>(
        cxb, wto, bo, x, ao, NTOK, HDIM, HDIM, 8);
    adaln_k<0, true><<<dim3(NTOK), blk, 0, stream>>>(
        ao, nullptr, nullptr, vol, ln1w, ln1b, gm1, be1, vs1w, vs1b, x1, x1b);
    gemm_hi_k<ACT_GELU, false, true><<<dim3(32 * 64), blk, 0, stream>>>(
        x1b, wtf1, fb1, nullptr, hb, NTOK, 4096, HDIM, 32);
    gemm_hi_k<ACT_NONE, false, false><<<dim3(8 * 64), blk, 0, stream>>>(
        hb, wtf2, fb2, nullptr, ffn, NTOK, HDIM, 4096, 8);
    gemm_hi_k<ACT_RELU, false, true><<<dim3(4 * 64), blk, 0, stream>>>(
        x1b, wtg1, gb1, nullptr, ghb, NTOK, 512, HDIM, 4);
    gemm_hi_k<ACT_SIG, false, false><<<dim3(8 * 64), blk, 0, stream>>>(
        ghb, wtg2, gb2, nullptr, gg, NTOK, HDIM, 512, 8);
    adaln_k<1, false><<<dim3(NTOK), blk, 0, stream>>>(
        x1, ffn, gg, vol, ln2w, ln2b, gm2, be2, vs2w, vs2b, (float*)d_out, nullptr);
}